// Round 20
// baseline (704.765 us; speedup 1.0000x reference)
//
#include <hip/hip_runtime.h>
#include <hip/hip_bf16.h>

#define NC 100000
#define NW 500
#define NE_CC 600000
#define NE_CW 25000
#define H 128
#define NL 3
#define DFF 512
#define DC 64

typedef __bf16 bf16x8 __attribute__((ext_vector_type(8)));
typedef float f32x4 __attribute__((ext_vector_type(4)));
#define MFMA16(a,b,c) __builtin_amdgcn_mfma_f32_16x16x32_bf16(a,b,c,0,0,0)

__device__ __forceinline__ float wsum(float v){
  #pragma unroll
  for (int o = 32; o; o >>= 1) v += __shfl_xor(v, o, 64);
  return v;
}
__device__ __forceinline__ float gsum16(float v){
  #pragma unroll
  for (int o = 1; o < 16; o <<= 1) v += __shfl_xor(v, o, 64);
  return v;
}
__device__ __forceinline__ float gmax16(float v){
  #pragma unroll
  for (int o = 1; o < 16; o <<= 1) v = fmaxf(v, __shfl_xor(v, o, 64));
  return v;
}

// async global->LDS, 16 B per lane; LDS dest = wave-uniform base + lane*16
__device__ __forceinline__ void gload16(const void* g, void* l){
  __builtin_amdgcn_global_load_lds(
      (const __attribute__((address_space(1))) void*)g,
      (__attribute__((address_space(3))) void*)l, 16, 0, 0);
}

// ======== fragment-major weight images ========
__global__ void prep_imgGW_k(const float* __restrict__ in, char* __restrict__ img, int nmat){
  int tot = nmat * 16384;
  for (int i = blockIdx.x * 256 + threadIdx.x; i < tot; i += gridDim.x * 256){
    int j = i & 7, lane = (i >> 3) & 63, f = (i >> 9) & 31, l = i >> 14;
    int lr = lane & 15, lk = lane >> 4;
    int ks = f >> 3, nt = f & 7;
    int k = ks * 32 + lk * 8 + j, n = nt * 16 + lr;
    float v = in[(size_t)l * 16384 + (size_t)k * 128 + n];
    *(__hip_bfloat16*)(img + (size_t)l * 32768 + f * 1024 + lane * 16 + j * 2) =
        __float2bfloat16(v);
  }
}
__global__ void prep_imgW1_k(const float* __restrict__ in, char* __restrict__ img){
  int tot = 3 * 65536;
  for (int i = blockIdx.x * 256 + threadIdx.x; i < tot; i += gridDim.x * 256){
    int j = i & 7, lane = (i >> 3) & 63, f = (i >> 9) & 15, ch = (i >> 13) & 7, l = i >> 16;
    int lr = lane & 15, lk = lane >> 4;
    int ks = f >> 2, nt = f & 3;
    int k = ks * 32 + lk * 8 + j, n = ch * 64 + nt * 16 + lr;
    float v = in[(size_t)l * 65536 + (size_t)k * 512 + n];
    *(__hip_bfloat16*)(img + (size_t)(l * 8 + ch) * 16384 + f * 1024 + lane * 16 + j * 2) =
        __float2bfloat16(v);
  }
}
__global__ void prep_imgW2_k(const float* __restrict__ in, char* __restrict__ img){
  int tot = 3 * 65536;
  for (int i = blockIdx.x * 256 + threadIdx.x; i < tot; i += gridDim.x * 256){
    int j = i & 7, lane = (i >> 3) & 63, f = (i >> 9) & 15, ch = (i >> 13) & 7, l = i >> 16;
    int lr = lane & 15, lk = lane >> 4;
    int ks = f >> 3, nt = f & 7;
    int k = ch * 64 + ks * 32 + lk * 8 + j, n = nt * 16 + lr;
    float v = in[(size_t)l * 65536 + (size_t)k * 128 + n];
    *(__hip_bfloat16*)(img + (size_t)(l * 8 + ch) * 16384 + f * 1024 + lane * 16 + j * 2) =
        __float2bfloat16(v);
  }
}

// ---------- fused cell embed + LN1 ----------
__global__ __launch_bounds__(256) void embed_ln_k(const float* __restrict__ x,
    const float* __restrict__ W, const float* __restrict__ b,
    const float* __restrict__ g, const float* __restrict__ lb,
    float* __restrict__ h, __hip_bfloat16* __restrict__ xn, int M)
{
  int lane = threadIdx.x & 63, wid = threadIdx.x >> 6;
  float w0[32], w1[32];
  #pragma unroll
  for (int k = 0; k < 32; k++){
    w0[k] = W[k * 128 + lane];
    w1[k] = W[k * 128 + 64 + lane];
  }
  float b0 = b[lane], b1 = b[lane + 64];
  float g0 = g[lane], g1 = g[lane + 64];
  float e0 = lb[lane], e1 = lb[lane + 64];
  for (int n = blockIdx.x * 4 + wid; n < M; n += gridDim.x * 4){
    const float4* xr = (const float4*)(x + (size_t)n * 32);
    float xs[32];
    #pragma unroll
    for (int q = 0; q < 8; q++){
      float4 t = xr[q];
      xs[4*q] = t.x; xs[4*q+1] = t.y; xs[4*q+2] = t.z; xs[4*q+3] = t.w;
    }
    float a0 = b0, a1 = b1;
    #pragma unroll
    for (int k = 0; k < 32; k++){ a0 += xs[k] * w0[k]; a1 += xs[k] * w1[k]; }
    h[(size_t)n * H + lane]      = a0;
    h[(size_t)n * H + lane + 64] = a1;
    float mu = wsum(a0 + a1) * (1.f / 128.f);
    float d0 = a0 - mu, d1 = a1 - mu;
    float var = wsum(d0 * d0 + d1 * d1) * (1.f / 128.f);
    float rs = rsqrtf(var + 1e-5f);
    xn[(size_t)n * H + lane]      = __float2bfloat16(d0 * rs * g0 + e0);
    xn[(size_t)n * H + lane + 64] = __float2bfloat16(d1 * rs * g1 + e1);
  }
}

// ---------- well embedding ----------
template<int K>
__global__ __launch_bounds__(256) void embed_k(const float* __restrict__ x,
    const float* __restrict__ W, const float* __restrict__ b,
    float* __restrict__ h, int M)
{
  __shared__ float sW[K * 128];
  for (int t = threadIdx.x; t < K * 128; t += 256) sW[t] = W[t];
  __syncthreads();
  int j = threadIdx.x & 127, half = threadIdx.x >> 7;
  float bj = b[j];
  for (int n = blockIdx.x * 2 + half; n < M; n += gridDim.x * 2){
    const float* xr = x + (size_t)n * K;
    float acc = bj;
    #pragma unroll
    for (int k = 0; k < K; k++) acc += xr[k] * sW[k * 128 + j];
    h[(size_t)n * H + j] = acc;
  }
}

// ---------- per-layer scalar edge coefficients ----------
__global__ void coeff_k(const float* __restrict__ gWe, const float* __restrict__ gae,
    const float* __restrict__ Wee, const float* __restrict__ bee, float* __restrict__ coeff)
{
  __shared__ float red[4];
  int t = threadIdx.x;
  for (int i = 0; i < NL; i++){
    const float* Wr = gWe + ((size_t)i * H + t) * H;
    const float* ga = gae + (size_t)i * H;
    float w = 0.f;
    for (int k = 0; k < H; k++) w += Wr[k] * ga[k];
    float pc = Wee[t] * w, pd = bee[t] * w;
    pc = wsum(pc); pd = wsum(pd);
    if ((t & 63) == 0){ red[(t >> 6) * 2 + 0] = pc; red[(t >> 6) * 2 + 1] = pd; }
    __syncthreads();
    if (t == 0){ coeff[i] = red[0] + red[2]; coeff[NL + i] = red[1] + red[3]; }
    __syncthreads();
  }
}

// ---------- dot product per node (wells only) ----------
__global__ __launch_bounds__(256) void dot2_k(const float* __restrict__ X,
    const float* __restrict__ va, float* __restrict__ oa, int M)
{
  int lane = threadIdx.x & 63, wid = threadIdx.x >> 6;
  int n = blockIdx.x * 4 + wid;
  if (n >= M) return;
  const float* row = X + (size_t)n * H;
  float a = wsum(row[lane] * va[lane] + row[lane + 64] * va[lane + 64]);
  if (lane == 0) oa[n] = a;
}

// ---------- MFMA GEMM (layer 0): A in regs, frag-major W image -> LDS ----------
__global__ __launch_bounds__(512, 4) void gemm_mfma_k(
    const __hip_bfloat16* __restrict__ A, const char* __restrict__ Wimg,
    __hip_bfloat16* __restrict__ Cbf,
    const float* __restrict__ va, const float* __restrict__ vb,
    float* __restrict__ oa, float* __restrict__ ob, int M)
{
  __shared__ uint4 sW4[2048];
  char* sW = (char*)sW4;
  const int tid = threadIdx.x;
  const int lane = tid & 63, w = tid >> 6;
  const int n0 = blockIdx.x * 128;
  const int rw = w * 16;
  const int lr = lane & 15, lk = lane >> 4;

  {
    int go = w * 1024 + lane * 16;
    #pragma unroll
    for (int q = 0; q < 4; q++)
      gload16(Wimg + q * 8192 + go, sW + q * 8192 + w * 1024);
  }

  const int arow = n0 + rw + lr;
  bf16x8 aX[4];
  if (arow < M){
    #pragma unroll
    for (int ks = 0; ks < 4; ks++)
      aX[ks] = *(const bf16x8*)(A + (size_t)arow * 128 + ks * 32 + lk * 8);
  } else {
    #pragma unroll
    for (int ks = 0; ks < 4; ks++) aX[ks] = (bf16x8){0,0,0,0,0,0,0,0};
  }
  __syncthreads();

  f32x4 acc[8];
  #pragma unroll
  for (int i = 0; i < 8; i++) acc[i] = (f32x4){0.f, 0.f, 0.f, 0.f};
  #pragma unroll
  for (int ks = 0; ks < 4; ks++){
    #pragma unroll
    for (int nt = 0; nt < 8; nt++){
      bf16x8 b = *(const bf16x8*)(sW + ((ks << 3) + nt) * 1024 + (lane << 4));
      acc[nt] = MFMA16(aX[ks], b, acc[nt]);
    }
  }
  #pragma unroll
  for (int nt = 0; nt < 8; nt++){
    int col = nt * 16 + lr;
    #pragma unroll
    for (int r = 0; r < 4; r++){
      int row = n0 + rw + lk * 4 + r;
      if (row < M) Cbf[(size_t)row * 128 + col] = __float2bfloat16(acc[nt][r]);
    }
  }
  {
    float vac[8], vbc[8];
    #pragma unroll
    for (int nt = 0; nt < 8; nt++){
      vac[nt] = va[nt * 16 + lr];
      vbc[nt] = vb ? vb[nt * 16 + lr] : 0.f;
    }
    #pragma unroll
    for (int r = 0; r < 4; r++){
      float da = 0.f, db = 0.f;
      #pragma unroll
      for (int nt = 0; nt < 8; nt++){
        da += acc[nt][r] * vac[nt];
        db += acc[nt][r] * vbc[nt];
      }
      #pragma unroll
      for (int o = 1; o < 16; o <<= 1){
        da += __shfl_xor(da, o, 64);
        db += __shfl_xor(db, o, 64);
      }
      int row = n0 + rw + lk * 4 + r;
      if (lr == 0 && row < M){
        oa[row] = da;
        if (ob) ob[row] = db;
      }
    }
  }
}

// ---------- MEGA v2: GAT(i) + FFN(i) + GEMM(i+1), 48 KB LDS (3 blocks/CU) ----------
__global__ __launch_bounds__(512, 6) void mega_k(
    const int* __restrict__ incl, const int* __restrict__ csr,
    const int* __restrict__ src, const float* __restrict__ attr,
    const float* __restrict__ coeff, int ci,
    const float* __restrict__ as_in, const float* __restrict__ ad_in,
    const __hip_bfloat16* __restrict__ X,
    const float* __restrict__ gbv,
    const float* __restrict__ n2gv, const float* __restrict__ n2bv,
    float* __restrict__ h,
    const char* __restrict__ W1img, const float* __restrict__ b1,
    const char* __restrict__ W2img, const float* __restrict__ b2,
    const float* __restrict__ lng, const float* __restrict__ lnb,
    const char* __restrict__ Wg,
    const float* __restrict__ va, const float* __restrict__ vb,
    float* __restrict__ oa, float* __restrict__ ob,
    __hip_bfloat16* __restrict__ Cbf, int mode, int M)
{
  __shared__ uint4 sW1_4[1024];   // 16 KB (single-buffered)
  __shared__ uint4 sW2_4[1024];   // 16 KB
  __shared__ uint4 sT4[1024];     // 16 KB
  char* sT = (char*)sT4;
  const int tid = threadIdx.x;
  const int lane = tid & 63, w = tid >> 6;
  const int n0 = blockIdx.x * 128;
  const int rw = w * 16;
  const int lr = lane & 15, lk = lane >> 4;
  const int gl = lane & 15, grp = lane >> 4;
  const int go = w * 1024 + lane * 16;
  const int lo = w * 1024;
  char* sTw = sT + w * 2048;
  // phase-A A-image aliases the weight buffers (dead until chunk-0 staging)
  char* aimgW = (w < 4) ? ((char*)sW1_4 + w * 4096)
                        : ((char*)sW2_4 + (w - 4) * 4096);

  const float c0 = coeff[ci], c1 = coeff[NL + ci];
  const int gbase = grp << 4;
  const int nb = n0 + w * 16 + grp * 4;

#define GACC2(A, U, P) \
    A[0] += (P) * __uint_as_float((U).x << 16); \
    A[1] += (P) * __uint_as_float((U).x & 0xffff0000u); \
    A[2] += (P) * __uint_as_float((U).y << 16); \
    A[3] += (P) * __uint_as_float((U).y & 0xffff0000u); \
    A[4] += (P) * __uint_as_float((U).z << 16); \
    A[5] += (P) * __uint_as_float((U).z & 0xffff0000u); \
    A[6] += (P) * __uint_as_float((U).w << 16); \
    A[7] += (P) * __uint_as_float((U).w & 0xffff0000u);

#define NODE_EPI(Q, ACC) { \
    int n = nb + (Q); \
    char* adst = aimgW + ((gl >> 2) << 10) + ((((gl & 3) << 4) + grp * 4 + (Q)) << 4); \
    if (n >= M){ *(uint4*)adst = make_uint4(0u,0u,0u,0u); } else { \
      float inv = (s4[Q] == 0.f) ? 0.f : 1.f / s4[Q]; \
      int j0 = gl * 8; \
      float4 h0 = *(float4*)&h[(size_t)n * H + j0]; \
      float4 h1 = *(float4*)&h[(size_t)n * H + j0 + 4]; \
      float4 g0 = *(const float4*)&gbv[j0]; \
      float4 g1 = *(const float4*)&gbv[j0 + 4]; \
      float hv[8]; \
      hv[0] = h0.x + ACC[0]*inv + g0.x; hv[1] = h0.y + ACC[1]*inv + g0.y; \
      hv[2] = h0.z + ACC[2]*inv + g0.z; hv[3] = h0.w + ACC[3]*inv + g0.w; \
      hv[4] = h1.x + ACC[4]*inv + g1.x; hv[5] = h1.y + ACC[5]*inv + g1.y; \
      hv[6] = h1.z + ACC[6]*inv + g1.z; hv[7] = h1.w + ACC[7]*inv + g1.w; \
      float ls = 0.f; \
      _Pragma("unroll") for (int i = 0; i < 8; i++) ls += hv[i]; \
      float mu = gsum16(ls) * (1.f / H); \
      float vs = 0.f; \
      _Pragma("unroll") for (int i = 0; i < 8; i++){ float d = hv[i]-mu; vs += d*d; } \
      float var = gsum16(vs) * (1.f / H); \
      float rsq = rsqrtf(var + 1e-5f); \
      float4 o0, o1; \
      o0.x=hv[0]; o0.y=hv[1]; o0.z=hv[2]; o0.w=hv[3]; \
      o1.x=hv[4]; o1.y=hv[5]; o1.z=hv[6]; o1.w=hv[7]; \
      *(float4*)&h[(size_t)n * H + j0] = o0; \
      *(float4*)&h[(size_t)n * H + j0 + 4] = o1; \
      float4 gg0 = *(const float4*)&n2gv[j0]; \
      float4 gg1 = *(const float4*)&n2gv[j0 + 4]; \
      float4 bb0 = *(const float4*)&n2bv[j0]; \
      float4 bb1 = *(const float4*)&n2bv[j0 + 4]; \
      float xo[8]; \
      xo[0]=(hv[0]-mu)*rsq*gg0.x+bb0.x; xo[1]=(hv[1]-mu)*rsq*gg0.y+bb0.y; \
      xo[2]=(hv[2]-mu)*rsq*gg0.z+bb0.z; xo[3]=(hv[3]-mu)*rsq*gg0.w+bb0.w; \
      xo[4]=(hv[4]-mu)*rsq*gg1.x+bb1.x; xo[5]=(hv[5]-mu)*rsq*gg1.y+bb1.y; \
      xo[6]=(hv[6]-mu)*rsq*gg1.z+bb1.z; xo[7]=(hv[7]-mu)*rsq*gg1.w+bb1.w; \
      uint4 ow; unsigned* owp = (unsigned*)&ow; \
      _Pragma("unroll") for (int i = 0; i < 4; i++){ \
        __hip_bfloat16 lo2 = __float2bfloat16(xo[2*i]); \
        __hip_bfloat16 hi2 = __float2bfloat16(xo[2*i+1]); \
        owp[i] = ((unsigned)(*(unsigned short*)&hi2) << 16) | (*(unsigned short*)&lo2); \
      } \
      *(uint4*)adst = ow; \
    } }

  // ---- phase A (round-18 2-pair pipelined form) ----
  int beg4[4], cnt4[4];
  #pragma unroll
  for (int q = 0; q < 4; q++){
    int n = nb + q;
    if (n < M){
      int b0 = (n == 0) ? 0 : incl[n - 1];
      beg4[q] = b0;
      cnt4[q] = incl[n] - b0;
    } else { beg4[q] = 0; cnt4[q] = 0; }
  }
  bool big = (cnt4[0] > 16) || (cnt4[1] > 16) || (cnt4[2] > 16) || (cnt4[3] > 16);

  if (!__any(big)){
    float adn4[4];
    #pragma unroll
    for (int q = 0; q < 4; q++) adn4[q] = (nb + q < M) ? ad_in[nb + q] : 0.f;
    int e4[4];
    #pragma unroll
    for (int q = 0; q < 4; q++) e4[q] = (gl < cnt4[q]) ? csr[beg4[q] + gl] : 0;
    int sv4[4];
    #pragma unroll
    for (int q = 0; q < 4; q++) sv4[q] = (gl < cnt4[q]) ? src[e4[q]] : 0;
    float at4[4];
    #pragma unroll
    for (int q = 0; q < 4; q++) at4[q] = (gl < cnt4[q]) ? attr[e4[q]] : 0.f;
    float as4[4];
    #pragma unroll
    for (int q = 0; q < 4; q++) as4[q] = (gl < cnt4[q]) ? as_in[sv4[q]] : 0.f;
    float p4[4], s4[4];
    #pragma unroll
    for (int q = 0; q < 4; q++){
      bool v = gl < cnt4[q];
      float a = v ? (as4[q] + adn4[q] + at4[q] * c0 + c1) : -1e30f;
      a = (a > 0.f) ? a : 0.2f * a;
      float mq = gmax16(a);
      float p = v ? expf(a - mq) : 0.f;
      s4[q] = gsum16(p);
      p4[q] = p;
    }
    #pragma unroll
    for (int qp = 0; qp < 2; qp++){
      const int q0 = qp * 2, q1 = qp * 2 + 1;
      float accA[8], accB[8];
      #pragma unroll
      for (int i = 0; i < 8; i++){ accA[i] = 0.f; accB[i] = 0.f; }
      int cm = max(cnt4[q0], cnt4[q1]);
      for (int t = 0; t < cm; t += 2){
        float pa0 = __shfl(p4[q0], gbase + t, 64);
        float pb0 = __shfl(p4[q1], gbase + t, 64);
        float pa1 = __shfl(p4[q0], gbase + t + 1, 64);
        float pb1 = __shfl(p4[q1], gbase + t + 1, 64);
        int sa0 = __shfl(sv4[q0], gbase + t, 64);
        int sb0 = __shfl(sv4[q1], gbase + t, 64);
        int sa1 = __shfl(sv4[q0], gbase + t + 1, 64);
        int sb1 = __shfl(sv4[q1], gbase + t + 1, 64);
        uint4 ua0 = *(const uint4*)(X + (size_t)sa0 * H + gl * 8);
        uint4 ub0 = *(const uint4*)(X + (size_t)sb0 * H + gl * 8);
        uint4 ua1 = *(const uint4*)(X + (size_t)sa1 * H + gl * 8);
        uint4 ub1 = *(const uint4*)(X + (size_t)sb1 * H + gl * 8);
        GACC2(accA, ua0, pa0) GACC2(accB, ub0, pb0)
        GACC2(accA, ua1, pa1) GACC2(accB, ub1, pb1)
      }
      NODE_EPI(q0, accA)
      NODE_EPI(q1, accB)
    }
  } else {
    for (int q = 0; q < 4; q++){
      int n = nb + q;
      char* adst = aimgW + ((gl >> 2) << 10) + ((((gl & 3) << 4) + grp * 4 + q) << 4);
      if (n >= M){ *(uint4*)adst = make_uint4(0u,0u,0u,0u); continue; }
      int beg = beg4[q];
      int end = beg4[q] + cnt4[q];
      float adn = ad_in[n];
      float m = -1e30f, s = 0.f;
      float acc[8];
      #pragma unroll
      for (int i = 0; i < 8; i++) acc[i] = 0.f;
      for (int base = beg; base < end; base += 16){
        int idx = base + gl;
        bool valid = idx < end;
        int e = valid ? csr[idx] : 0;
        int sv = valid ? src[e] : 0;
        float a = -1e30f;
        if (valid){
          a = as_in[sv] + adn + attr[e] * c0 + c1;
          a = (a > 0.f) ? a : 0.2f * a;
        }
        float cmx = gmax16(a);
        float nm = fmaxf(m, cmx);
        float sc = expf(m - nm);
        #pragma unroll
        for (int i = 0; i < 8; i++) acc[i] *= sc;
        s *= sc;
        float p = valid ? expf(a - nm) : 0.f;
        s += gsum16(p);
        m = nm;
        int cnt = min(16, end - base);
        for (int t = 0; t < cnt; t++){
          float pt = __shfl(p, gbase + t, 64);
          int st = __shfl(sv, gbase + t, 64);
          uint4 u = *(const uint4*)(X + (size_t)st * H + gl * 8);
          GACC2(acc, u, pt)
        }
      }
      float s4q = s;
      float s4[4]; s4[q] = s4q;
      NODE_EPI(q, acc)
    }
  }
#undef GACC2

  // A-image complete -> load aX fragments; then free the buffers for staging
  asm volatile("s_waitcnt lgkmcnt(0)" ::: "memory");
  bf16x8 aX[4];
  #pragma unroll
  for (int ks = 0; ks < 4; ks++)
    aX[ks] = *(const bf16x8*)(aimgW + (ks << 10) + (lane << 4));
  asm volatile("s_waitcnt lgkmcnt(0) vmcnt(0)" ::: "memory");
  __builtin_amdgcn_s_barrier();   // all waves done with aimg; h stores flushed

  // stage chunk 0 into (single) weight buffers
  gload16(W1img + go,        (char*)sW1_4 + lo);
  gload16(W1img + 8192 + go, (char*)sW1_4 + 8192 + lo);
  gload16(W2img + go,        (char*)sW2_4 + lo);
  gload16(W2img + 8192 + go, (char*)sW2_4 + 8192 + lo);
  asm volatile("s_waitcnt vmcnt(0)" ::: "memory");
  __builtin_amdgcn_s_barrier();

  f32x4 acc2[8];
  #pragma unroll
  for (int i = 0; i < 8; i++) acc2[i] = (f32x4){0.f, 0.f, 0.f, 0.f};

  const int rdA = ((lane ^ ((lane >> 3) & 7)) << 4);

  for (int ch = 0; ch < DFF / DC; ch++){
    const char* W1c = (const char*)sW1_4;
    const char* W2c = (const char*)sW2_4;

    f32x4 acc1[4];
    #pragma unroll
    for (int i = 0; i < 4; i++) acc1[i] = (f32x4){0.f, 0.f, 0.f, 0.f};
    #pragma unroll
    for (int ks = 0; ks < 4; ks++){
      #pragma unroll
      for (int nt = 0; nt < 4; nt++){
        bf16x8 b = *(const bf16x8*)(W1c + ((ks << 2) + nt) * 1024 + (lane << 4));
        acc1[nt] = MFMA16(aX[ks], b, acc1[nt]);
      }
    }
    #pragma unroll
    for (int nt = 0; nt < 4; nt++){
      int col = nt * 16 + lr;
      float bb = b1[ch * DC + col];
      int ksp = col >> 5;
      int qhi = ((col >> 3) & 3) << 4;
      int jb  = (col & 7) << 1;
      #pragma unroll
      for (int r = 0; r < 4; r++){
        int slot = qhi + lk * 4 + r;
        int slotp = slot ^ ((slot >> 3) & 7);
        float v = fmaxf(acc1[nt][r] + bb, 0.f);
        *(__hip_bfloat16*)(sTw + (ksp << 10) + (slotp << 4) + jb) = __float2bfloat16(v);
      }
    }
    asm volatile("s_waitcnt lgkmcnt(0)" ::: "memory");

    #pragma unroll
    for (int ks = 0; ks < 2; ks++){
      bf16x8 a = *(const bf16x8*)(sTw + (ks << 10) + rdA);
      #pragma unroll
      for (int nt = 0; nt < 8; nt++){
        bf16x8 b = *(const bf16x8*)(W2c + ((ks << 3) + nt) * 1024 + (lane << 4));
        acc2[nt] = MFMA16(a, b, acc2[nt]);
      }
    }
    if (ch < DFF / DC - 1){
      __builtin_amdgcn_s_barrier();   // all waves done reading this chunk
      const char* g1 = W1img + (size_t)(ch + 1) * 16384;
      const char* g2 = W2img + (size_t)(ch + 1) * 16384;
      gload16(g1 + go,        (char*)sW1_4 + lo);
      gload16(g1 + 8192 + go, (char*)sW1_4 + 8192 + lo);
      gload16(g2 + go,        (char*)sW2_4 + lo);
      gload16(g2 + 8192 + go, (char*)sW2_4 + 8192 + lo);
      asm volatile("s_waitcnt vmcnt(0)" ::: "memory");
      __builtin_amdgcn_s_barrier();
    }
  }

  __builtin_amdgcn_s_barrier();   // all waves done reading ch7 weights
  // stage Wg (32 KB) into sW1+sW2; overlaps epilogue's global reads
  gload16(Wg + go,         (char*)sW1_4 + lo);
  gload16(Wg + 8192 + go,  (char*)sW1_4 + 8192 + lo);
  gload16(Wg + 16384 + go, (char*)sW2_4 + lo);
  gload16(Wg + 24576 + go, (char*)sW2_4 + 8192 + lo);

  // epilogue: val = h + acc2 + b2; h write (mode 0); xo lo-half -> sT, hi-half packed
  float b2c[8];
  #pragma unroll
  for (int nt = 0; nt < 8; nt++) b2c[nt] = b2[nt * 16 + lr];
  float lngc[8], lnbc[8];
  if (mode == 0){
    #pragma unroll
    for (int nt = 0; nt < 8; nt++){
      lngc[nt] = lng[nt * 16 + lr];
      lnbc[nt] = lnb[nt * 16 + lr];
    }
  }

  unsigned xh01[4], xh23[4];   // packed bf16 pairs for nt {4,5} and {6,7}, per r

  #pragma unroll
  for (int r = 0; r < 4; r++){
    int row = n0 + rw + lk * 4 + r;
    bool ok = row < M;
    float val[8]; float sum = 0.f;
    #pragma unroll
    for (int nt = 0; nt < 8; nt++){
      int col = nt * 16 + lr;
      float hv = ok ? h[(size_t)row * 128 + col] : 0.f;
      val[nt] = hv + acc2[nt][r] + b2c[nt];
      sum += val[nt];
    }
    float mu = 0.f, rs = 1.f;
    if (mode == 0){
      #pragma unroll
      for (int o = 1; o < 16; o <<= 1) sum += __shfl_xor(sum, o, 64);
      mu = sum * (1.f / 128.f);
      float vs = 0.f;
      #pragma unroll
      for (int nt = 0; nt < 8; nt++){ float d = val[nt] - mu; vs += d * d; }
      #pragma unroll
      for (int o = 1; o < 16; o <<= 1) vs += __shfl_xor(vs, o, 64);
      rs = rsqrtf(vs * (1.f / 128.f) + 1e-5f);
    }
    float xo8[8];
    #pragma unroll
    for (int nt = 0; nt < 8; nt++){
      int col = nt * 16 + lr;
      if (mode == 0 && ok) h[(size_t)row * 128 + col] = val[nt];
      xo8[nt] = (mode == 0) ? ((val[nt] - mu) * rs * lngc[nt] + lnbc[nt]) : val[nt];
    }
    // lo half (nt 0..3 -> frags 0,1) into sTw now
    #pragma unroll
    for (int nt = 0; nt < 4; nt++){
      int lanep = ((((nt & 1) << 1) + (lr >> 3)) << 4) + (lk << 2) + r;
      *(__hip_bfloat16*)(sTw + ((nt >> 1) << 10) + (lanep << 4) + ((lr & 7) << 1)) =
          __float2bfloat16(xo8[nt]);
    }
    // hi half packed into regs
    {
      __hip_bfloat16 a4 = __float2bfloat16(xo8[4]);
      __hip_bfloat16 a5 = __float2bfloat16(xo8[5]);
      __hip_bfloat16 a6 = __float2bfloat16(xo8[6]);
      __hip_bfloat16 a7 = __float2bfloat16(xo8[7]);
      xh01[r] = ((unsigned)(*(unsigned short*)&a5) << 16) | (*(unsigned short*)&a4);
      xh23[r] = ((unsigned)(*(unsigned short*)&a7) << 16) | (*(unsigned short*)&a6);
    }
  }
  asm volatile("s_waitcnt lgkmcnt(0)" ::: "memory");
  bf16x8 aG0 = *(const bf16x8*)(sTw + (lane << 4));
  bf16x8 aG1 = *(const bf16x8*)(sTw + 1024 + (lane << 4));
  asm volatile("s_waitcnt lgkmcnt(0) vmcnt(0)" ::: "memory");
  __builtin_amdgcn_s_barrier();   // Wg fully staged

  f32x4 accG[8];
  #pragma unroll
  for (int i = 0; i < 8; i++) accG[i] = (f32x4){0.f, 0.f, 0.f, 0.f};
  // pass 0: ks 0,1 (B frags 0..15 in sW1)
  #pragma unroll
  for (int nt = 0; nt < 8; nt++){
    bf16x8 b0 = *(const bf16x8*)((const char*)sW1_4 + (nt << 10) + (lane << 4));
    accG[nt] = MFMA16(aG0, b0, accG[nt]);
  }
  #pragma unroll
  for (int nt = 0; nt < 8; nt++){
    bf16x8 b1v = *(const bf16x8*)((const char*)sW1_4 + ((8 + nt) << 10) + (lane << 4));
    accG[nt] = MFMA16(aG1, b1v, accG[nt]);
  }
  // pass 1: write hi-half xo into sTw (wave-private; pass-0 reads already done)
  #pragma unroll
  for (int r = 0; r < 4; r++){
    #pragma unroll
    for (int i = 0; i < 4; i++){
      int nt = 4 + i;
      unsigned word = (i < 2) ? xh01[r] : xh23[r];
      unsigned short bits = (unsigned short)((i & 1) ? (word >> 16) : (word & 0xffffu));
      int lanep = ((((nt & 1) << 1) + (lr >> 3)) << 4) + (lk << 2) + r;
      *(unsigned short*)(sTw + (((nt >> 1) & 1) << 10) + (lanep << 4) + ((lr & 7) << 1)) = bits;
    }
  }
  asm volatile("s_waitcnt lgkmcnt(0)" ::: "memory");
  bf16x8 aG2 = *(const bf16x8*)(sTw + (lane << 4));
  bf16x8 aG3 = *(const bf16x8*)(sTw + 1024 + (lane << 4));
  asm volatile("s_waitcnt lgkmcnt(0)" ::: "memory");
  #pragma unroll
  for (int nt = 0; nt < 8; nt++){
    bf16x8 b2v = *(const bf16x8*)((const char*)sW2_4 + (nt << 10) + (lane << 4));
    accG[nt] = MFMA16(aG2, b2v, accG[nt]);
  }
  #pragma unroll
  for (int nt = 0; nt < 8; nt++){
    bf16x8 b3 = *(const bf16x8*)((const char*)sW2_4 + ((8 + nt) << 10) + (lane << 4));
    accG[nt] = MFMA16(aG3, b3, accG[nt]);
  }

  #pragma unroll
  for (int nt = 0; nt < 8; nt++){
    int col = nt * 16 + lr;
    #pragma unroll
    for (int r = 0; r < 4; r++){
      int row = n0 + rw + lk * 4 + r;
      if (row < M) Cbf[(size_t)row * 128 + col] = __float2bfloat16(accG[nt][r]);
    }
  }
  {
    float vac[8], vbc[8];
    #pragma unroll
    for (int nt = 0; nt < 8; nt++){
      vac[nt] = va[nt * 16 + lr];
      vbc[nt] = vb ? vb[nt * 16 + lr] : 0.f;
    }
    #pragma unroll
    for (int r = 0; r < 4; r++){
      float da = 0.f, db = 0.f;
      #pragma unroll
      for (int nt = 0; nt < 8; nt++){
        da += accG[nt][r] * vac[nt];
        db += accG[nt][r] * vbc[nt];
      }
      #pragma unroll
      for (int o = 1; o < 16; o <<= 1){
        da += __shfl_xor(da, o, 64);
        db += __shfl_xor(db, o, 64);
      }
      int row = n0 + rw + lk * 4 + r;
      if (lr == 0 && row < M){
        oa[row] = da;
        if (ob) ob[row] = db;
      }
    }
  }
#undef NODE_EPI
}

// ---------- fp32 GEMM (tiny well matmul) ----------
__global__ __launch_bounds__(256) void gemm128_k(const float* __restrict__ A,
    const float* __restrict__ Bm, float* __restrict__ C, int M)
{
  __shared__ float sB[32 * 128];
  __shared__ float sA[64 * 33];
  const int tid = threadIdx.x;
  const int n0 = blockIdx.x * 64;
  const int j4 = (tid & 31) * 4;
  const int rB = (tid >> 5) * 8;
  float acc[8][4];
  #pragma unroll
  for (int r = 0; r < 8; r++){ acc[r][0]=acc[r][1]=acc[r][2]=acc[r][3]=0.f; }
  for (int kc = 0; kc < 128; kc += 32){
    for (int t = tid; t < 4096; t += 256){
      int kk = t >> 7, j = t & 127;
      sB[kk * 128 + j] = Bm[(size_t)(kc + kk) * H + j];
    }
    for (int t = tid; t < 2048; t += 256){
      int n = t >> 5, kk = t & 31; int row = n0 + n;
      sA[n * 33 + kk] = (row < M) ? A[(size_t)row * H + kc + kk] : 0.f;
    }
    __syncthreads();
    #pragma unroll 8
    for (int kk = 0; kk < 32; kk++){
      float4 bv = *(const float4*)&sB[kk * 128 + j4];
      #pragma unroll
      for (int r = 0; r < 8; r++){
        float av = sA[(rB + r) * 33 + kk];
        acc[r][0] += av * bv.x; acc[r][1] += av * bv.y;
        acc[r][2] += av * bv.z; acc[r][3] += av * bv.w;
      }
    }
    __syncthreads();
  }
  #pragma unroll
  for (int r = 0; r < 8; r++){
    int row = n0 + rB + r;
    if (row < M){
      float4 o; o.x = acc[r][0]; o.y = acc[r][1]; o.z = acc[r][2]; o.w = acc[r][3];
      *(float4*)&C[(size_t)row * H + j4] = o;
    }
  }
}

// ---------- CSR build ----------
__global__ void count_k(const int* __restrict__ dst, int* __restrict__ cnt, int NE){
  int e = blockIdx.x * 256 + threadIdx.x;
  if (e < NE) atomicAdd(&cnt[dst[e]], 1);
}
__global__ void scan1_k(const int* __restrict__ in, int* __restrict__ out,
                        int* __restrict__ bsum, int N){
  __shared__ int sd[256];
  int tid = threadIdx.x;
  int base = blockIdx.x * 1024 + tid * 4;
  int v0 = (base + 0 < N) ? in[base + 0] : 0;
  int v1 = (base + 1 < N) ? in[base + 1] : 0;
  int v2 = (base + 2 < N) ? in[base + 2] : 0;
  int v3 = (base + 3 < N) ? in[base + 3] : 0;
  sd[tid] = v0 + v1 + v2 + v3;
  __syncthreads();
  for (int off = 1; off < 256; off <<= 1){
    int t = (tid >= off) ? sd[tid - off] : 0;
    __syncthreads();
    sd[tid] += t;
    __syncthreads();
  }
  int run = (tid > 0) ? sd[tid - 1] : 0;
  run += v0; if (base + 0 < N) out[base + 0] = run;
  run += v1; if (base + 1 < N) out[base + 1] = run;
  run += v2; if (base + 2 < N) out[base + 2] = run;
  run += v3; if (base + 3 < N) out[base + 3] = run;
  if (tid == 255) bsum[blockIdx.x] = sd[255];
}
__global__ void scan2_k(int* __restrict__ bs, int NB){
  __shared__ int sd[256];
  int tid = threadIdx.x;
  int base = tid * 4;
  int v0 = (base + 0 < NB) ? bs[base + 0] : 0;
  int v1 = (base + 1 < NB) ? bs[base + 1] : 0;
  int v2 = (base + 2 < NB) ? bs[base + 2] : 0;
  int v3 = (base + 3 < NB) ? bs[base + 3] : 0;
  sd[tid] = v0 + v1 + v2 + v3;
  __syncthreads();
  for (int off = 1; off < 256; off <<= 1){
    int t = (tid >= off) ? sd[tid - off] : 0;
    __syncthreads();
    sd[tid] += t;
    __syncthreads();
  }
  int run = (tid > 0) ? sd[tid - 1] : 0;
  run += v0; if (base + 0 < NB) bs[base + 0] = run;
  run += v1; if (base + 1 < NB) bs[base + 1] = run;
  run += v2; if (base + 2 < NB) bs[base + 2] = run;
  run += v3; if (base + 3 < NB) bs[base + 3] = run;
}
__global__ void scan3_k(int* __restrict__ out, const int* __restrict__ bsum, int N){
  int b = blockIdx.x;
  if (b == 0) return;
  int add = bsum[b - 1];
  int i = b * 1024 + threadIdx.x * 4;
  #pragma unroll
  for (int j = 0; j < 4; j++) if (i + j < N) out[i + j] += add;
}
__global__ void initfill_k(const int* __restrict__ incl, int* __restrict__ fill, int N){
  int i = blockIdx.x * 256 + threadIdx.x;
  if (i < N) fill[i] = (i == 0) ? 0 : incl[i - 1];
}
__global__ void fill_k(const int* __restrict__ dst, int* __restrict__ fill,
                       int* __restrict__ csr, int NE){
  int e = blockIdx.x * 256 + threadIdx.x;
  if (e < NE){
    int p = atomicAdd(&fill[dst[e]], 1);
    csr[p] = e;
  }
}

// ---------- standalone GAT gather (wells only, no residual) ----------
__global__ __launch_bounds__(256) void gat_k(
    const int* __restrict__ incl, const int* __restrict__ csr,
    const int* __restrict__ src,
    const float* __restrict__ as_, const float* __restrict__ ad_,
    const __hip_bfloat16* __restrict__ X, float* __restrict__ hout, int M)
{
  int lane = threadIdx.x & 63, wid = threadIdx.x >> 6;
  int grp = lane >> 4, gl = lane & 15;
  int n = blockIdx.x * 16 + wid * 4 + grp;
  if (n >= M) return;
  int beg = (n == 0) ? 0 : incl[n - 1];
  int end = incl[n];
  float adn = ad_[n];
  const int gbase = grp << 4;
  float m = -1e30f, s = 0.f;
  float acc[8];
  #pragma unroll
  for (int i = 0; i < 8; i++) acc[i] = 0.f;
#define GACC(U, P) \
    acc[0] += (P) * __uint_as_float((U).x << 16); \
    acc[1] += (P) * __uint_as_float((U).x & 0xffff0000u); \
    acc[2] += (P) * __uint_as_float((U).y << 16); \
    acc[3] += (P) * __uint_as_float((U).y & 0xffff0000u); \
    acc[4] += (P) * __uint_as_float((U).z << 16); \
    acc[5] += (P) * __uint_as_float((U).z & 0xffff0000u); \
    acc[6] += (P) * __uint_as_float((U).w << 16); \
    acc[7] += (P) * __uint_as_float((U).w & 0xffff0000u);
  for (int base = beg; base < end; base += 16){
    int idx = base + gl;
    bool valid = idx < end;
    int e = valid ? csr[idx] : 0;
    int sv = valid ? src[e] : 0;
    float a = -1e30f;
    if (valid){
      a = as_[sv] + adn;
      a = (a > 0.f) ? a : 0.2f * a;
    }
    float cm = gmax16(a);
    float nm = fmaxf(m, cm);
    float sc = expf(m - nm);
    #pragma unroll
    for (int i = 0; i < 8; i++) acc[i] *= sc;
    s *= sc;
    float p = valid ? expf(a - nm) : 0.f;
    s += gsum16(p);
    m = nm;
    int cnt = min(16, end - base);
    for (int t = 0; t < cnt; t++){
      float pt = __shfl(p, gbase + t, 64);
      int st = __shfl(sv, gbase + t, 64);
      uint4 u = *(const uint4*)(X + (size_t)st * H + gl * 8);
      GACC(u, pt)
    }
  }
#undef GACC
  float inv = (s == 0.f) ? 0.f : 1.f / s;
  int j0 = gl * 8;
  float4 o0, o1;
  o0.x = acc[0]*inv; o0.y = acc[1]*inv; o0.z = acc[2]*inv; o0.w = acc[3]*inv;
  o1.x = acc[4]*inv; o1.y = acc[5]*inv; o1.z = acc[6]*inv; o1.w = acc[7]*inv;
  *(float4*)&hout[(size_t)n * H + j0] = o0;
  *(float4*)&hout[(size_t)n * H + j0 + 4] = o1;
}

// ---------- final well MLP ----------
__global__ __launch_bounds__(128) void mlp_k(const float* __restrict__ hwell,
    const float* __restrict__ wb, const float* __restrict__ mW1,
    const float* __restrict__ mb1, const float* __restrict__ mW2,
    const float* __restrict__ mb2, float* __restrict__ out)
{
  __shared__ float sH[128], sT[128];
  int n = blockIdx.x, j = threadIdx.x;
  sH[j] = hwell[(size_t)n * H + j] + wb[j];
  __syncthreads();
  float a = mb1[j];
  for (int k = 0; k < 128; k++) a += sH[k] * mW1[k * 128 + j];
  sT[j] = fmaxf(a, 0.f);
  __syncthreads();
  if (j < 75){
    float o = mb2[j];
    for (int k = 0; k < 128; k++) o += sT[k] * mW2[k * 75 + j];
    out[(size_t)n * 75 + j] = o;
  }
}

extern "C" void kernel_launch(void* const* d_in, const int* in_sizes, int n_in,
                              void* d_out, int out_size, void* d_ws, size_t ws_size,
                              hipStream_t stream)
{
  (void)in_sizes; (void)n_in; (void)out_size; (void)ws_size;
  const float* cell_x = (const float*)d_in[0];
  const float* well_x = (const float*)d_in[1];
  const int*   eidx   = (const int*)d_in[2];
  const float* eattr  = (const float*)d_in[3];
  const int*   wsrc   = (const int*)d_in[4];
  const int*   wdst   = (const int*)d_in[5];
  const float* W_cell = (const float*)d_in[6];
  const float* b_cell = (const float*)d_in[7];
  const float* W_well = (const float*)d_in[8];
  const float* b_well = (const float*)d_in[9];
  const float* W_ee   = (const float*)d_in[10];
  const float* b_ee   = (const float*)d_in[11];
  const float* gW     = (const float*)d_in[12];
  const float* gas    = (const float*)d_in[13];
  const float* gad    = (const float*)d_in[14];
  const float* gae    = (const float*)d_in[15];
  const float* gWe    = (const float*)d_in[16];
  const float* gb     = (const float*)d_in[17];
  const float* n1g    = (const float*)d_in[18];
  const float* n1b    = (const float*)d_in[19];
  const float* fW1    = (const float*)d_in[20];
  const float* fb1    = (const float*)d_in[21];
  const float* fW2    = (const float*)d_in[22];
  const float* fb2    = (const float*)d_in[23];
  const float* n2g    = (const float*)d_in[24];
  const float* n2b    = (const float*)d_in[25];
  const float* wW     = (const float*)d_in[26];
  const float* was    = (const float*)d_in[27];
  const float* wad    = (const float*)d_in[28];
  const float* wb     = (const float*)d_in[29];
  const float* mW1    = (const float*)d_in[30];
  const float* mb1    = (const float*)d_in[31];
  const float* mW2    = (const float*)d_in[32];
  const float* mb2    = (const float*)d_in[33];

  const int* src = eidx;
  const int* dst = eidx + NE_CC;

  char* wsb = (char*)d_ws;
  size_t off = 0;
  auto alloc = [&](size_t bytes) -> void* {
    void* p = wsb + off; off += (bytes + 255) & ~(size_t)255; return p;
  };
  float* h      = (float*)alloc((size_t)NC * H * 4);
  __hip_bfloat16* xnbf  = (__hip_bfloat16*)alloc((size_t)NC * H * 2);
  __hip_bfloat16* hsbf0 = (__hip_bfloat16*)alloc((size_t)NC * H * 2);
  __hip_bfloat16* hsbf1 = (__hip_bfloat16*)alloc((size_t)NC * H * 2);
  float* as0    = (float*)alloc((size_t)NC * 4);
  float* ad0    = (float*)alloc((size_t)NC * 4);
  float* as1    = (float*)alloc((size_t)NC * 4);
  float* ad1    = (float*)alloc((size_t)NC * 4);
  float* hw     = (float*)alloc((size_t)NW * H * 4);
  float* hwp    = (float*)alloc((size_t)NW * H * 4);
  float* hwell  = (float*)alloc((size_t)NW * H * 4);
  float* coeff  = (float*)alloc(64);
  char* gWimg = (char*)alloc((size_t)NL * 32768);
  char* wWimg = (char*)alloc(32768);
  char* W1img = (char*)alloc((size_t)NL * 131072);
  char* W2img = (char*)alloc((size_t)NL * 131072);
  int* cntC  = (int*)alloc((size_t)NC * 4);
  int* inclC = (int*)alloc((size_t)NC * 4);
  int* fillC = (int*)alloc((size_t)NC * 4);
  int* csrC  = (int*)alloc((size_t)NE_CC * 4);
  int* inclW = (int*)alloc((size_t)NW * 4);
  int* fillW = (int*)alloc((size_t)NW * 4);
  int* csrW  = (int*)alloc((size_t)NE_CW * 4);
  int* bsum  = (int*)alloc(1024 * 4);

  const int eBlocks  = (NE_CC + 255) / 256;
  const int ewBlocks = (NE_CW + 255) / 256;
  const int NBC = (NC + 1023) / 1024;
  const int NBW = (NW + 1023) / 1024;

  // ---- CSR build (c2c) ----
  hipMemsetAsync(cntC, 0, (size_t)NC * 4, stream);
  count_k<<<eBlocks, 256, 0, stream>>>(dst, cntC, NE_CC);
  scan1_k<<<NBC, 256, 0, stream>>>(cntC, inclC, bsum, NC);
  scan2_k<<<1, 256, 0, stream>>>(bsum, NBC);
  scan3_k<<<NBC, 256, 0, stream>>>(inclC, bsum, NC);
  initfill_k<<<(NC + 255) / 256, 256, 0, stream>>>(inclC, fillC, NC);
  fill_k<<<eBlocks, 256, 0, stream>>>(dst, fillC, csrC, NE_CC);
  // ---- CSR build (c2w) ----
  hipMemsetAsync(fillW, 0, (size_t)NW * 4, stream);
  count_k<<<ewBlocks, 256, 0, stream>>>(wdst, fillW, NE_CW);
  scan1_k<<<NBW, 256, 0, stream>>>(fillW, inclW, bsum, NW);
  scan2_k<<<1, 256, 0, stream>>>(bsum, NBW);
  scan3_k<<<NBW, 256, 0, stream>>>(inclW, bsum, NW);
  initfill_k<<<(NW + 255) / 256, 256, 0, stream>>>(inclW, fillW, NW);
  fill_k<<<ewBlocks, 256, 0, stream>>>(wdst, fillW, csrW, NE_CW);

  // ---- weight image prep ----
  prep_imgGW_k<<<96, 256, 0, stream>>>(gW, gWimg, NL);
  prep_imgGW_k<<<32, 256, 0, stream>>>(wW, wWimg, 1);
  prep_imgW1_k<<<768, 256, 0, stream>>>(fW1, W1img);
  prep_imgW2_k<<<768, 256, 0, stream>>>(fW2, W2img);

  embed_ln_k<<<1024, 256, 0, stream>>>(cell_x, W_cell, b_cell, n1g, n1b, h, xnbf, NC);
  embed_k<16><<<250, 256, 0, stream>>>(well_x, W_well, b_well, hw, NW);
  coeff_k<<<1, 128, 0, stream>>>(gWe, gae, W_ee, b_ee, coeff);

  const int mfmaBlocks = (NC + 127) / 128;

  gemm_mfma_k<<<mfmaBlocks, 512, 0, stream>>>(xnbf, gWimg,
      hsbf0, gas, gad, as0, ad0, NC);

  for (int i = 0; i < NL; i++){
    const __hip_bfloat16* Xin = (i & 1) ? hsbf1 : hsbf0;
    __hip_bfloat16* Xout      = (i & 1) ? hsbf0 : hsbf1;
    const float* asi = (i & 1) ? as1 : as0;
    const float* adi = (i & 1) ? ad1 : ad0;
    float* aso = (i & 1) ? as0 : as1;
    float* ado = (i & 1) ? ad0 : ad1;
    if (i < NL - 1){
      mega_k<<<mfmaBlocks, 512, 0, stream>>>(inclC, csrC, src, eattr, coeff, i,
          asi, adi, Xin, gb + i * H, n2g + i * H, n2b + i * H, h,
          W1img + (size_t)i * 131072, fb1 + (size_t)i * DFF,
          W2img + (size_t)i * 131072, fb2 + (size_t)i * H,
          n1g + (i + 1) * H, n1b + (i + 1) * H,
          gWimg + (size_t)(i + 1) * 32768,
          gas + (i + 1) * H, gad + (i + 1) * H, aso, ado, Xout, 0, NC);
    } else {
      mega_k<<<mfmaBlocks, 512, 0, stream>>>(inclC, csrC, src, eattr, coeff, i,
          asi, adi, Xin, gb + i * H, n2g + i * H, n2b + i * H, h,
          W1img + (size_t)i * 131072, fb1 + (size_t)i * DFF,
          W2img + (size_t)i * 131072, fb2 + (size_t)i * H,
          n1g, n1b,
          wWimg, was, nullptr, aso, nullptr, Xout, 1, NC);
    }
  }

  gemm128_k<<<(NW + 63) / 64, 256, 0, stream>>>(hw, wW, hwp, NW);
  dot2_k<<<(NW + 3) / 4, 256, 0, stream>>>(hwp, wad, ad0, NW);
  gat_k<<<(NW + 15) / 16, 256, 0, stream>>>(inclW, csrW, wsrc,
      as1, ad0, hsbf1, hwell, NW);
  mlp_k<<<NW, 128, 0, stream>>>(hwell, wb, mW1, mb1, mW2, mb2, (float*)d_out);
}

// Round 21
// 584.233 us; speedup vs baseline: 1.2063x; 1.2063x over previous
//
#include <hip/hip_runtime.h>
#include <hip/hip_bf16.h>

#define NC 100000
#define NW 500
#define NE_CC 600000
#define NE_CW 25000
#define H 128
#define NL 3
#define DFF 512
#define DC 64

typedef __bf16 bf16x8 __attribute__((ext_vector_type(8)));
typedef float f32x4 __attribute__((ext_vector_type(4)));
#define MFMA16(a,b,c) __builtin_amdgcn_mfma_f32_16x16x32_bf16(a,b,c,0,0,0)

__device__ __forceinline__ float wsum(float v){
  #pragma unroll
  for (int o = 32; o; o >>= 1) v += __shfl_xor(v, o, 64);
  return v;
}
__device__ __forceinline__ float gsum16(float v){
  #pragma unroll
  for (int o = 1; o < 16; o <<= 1) v += __shfl_xor(v, o, 64);
  return v;
}
__device__ __forceinline__ float gmax16(float v){
  #pragma unroll
  for (int o = 1; o < 16; o <<= 1) v = fmaxf(v, __shfl_xor(v, o, 64));
  return v;
}

// async global->LDS, 16 B per lane; LDS dest = wave-uniform base + lane*16
__device__ __forceinline__ void gload16(const void* g, void* l){
  __builtin_amdgcn_global_load_lds(
      (const __attribute__((address_space(1))) void*)g,
      (__attribute__((address_space(3))) void*)l, 16, 0, 0);
}

// ======== fragment-major weight images ========
__global__ void prep_imgGW_k(const float* __restrict__ in, char* __restrict__ img, int nmat){
  int tot = nmat * 16384;
  for (int i = blockIdx.x * 256 + threadIdx.x; i < tot; i += gridDim.x * 256){
    int j = i & 7, lane = (i >> 3) & 63, f = (i >> 9) & 31, l = i >> 14;
    int lr = lane & 15, lk = lane >> 4;
    int ks = f >> 3, nt = f & 7;
    int k = ks * 32 + lk * 8 + j, n = nt * 16 + lr;
    float v = in[(size_t)l * 16384 + (size_t)k * 128 + n];
    *(__hip_bfloat16*)(img + (size_t)l * 32768 + f * 1024 + lane * 16 + j * 2) =
        __float2bfloat16(v);
  }
}
__global__ void prep_imgW1_k(const float* __restrict__ in, char* __restrict__ img){
  int tot = 3 * 65536;
  for (int i = blockIdx.x * 256 + threadIdx.x; i < tot; i += gridDim.x * 256){
    int j = i & 7, lane = (i >> 3) & 63, f = (i >> 9) & 15, ch = (i >> 13) & 7, l = i >> 16;
    int lr = lane & 15, lk = lane >> 4;
    int ks = f >> 2, nt = f & 3;
    int k = ks * 32 + lk * 8 + j, n = ch * 64 + nt * 16 + lr;
    float v = in[(size_t)l * 65536 + (size_t)k * 512 + n];
    *(__hip_bfloat16*)(img + (size_t)(l * 8 + ch) * 16384 + f * 1024 + lane * 16 + j * 2) =
        __float2bfloat16(v);
  }
}
__global__ void prep_imgW2_k(const float* __restrict__ in, char* __restrict__ img){
  int tot = 3 * 65536;
  for (int i = blockIdx.x * 256 + threadIdx.x; i < tot; i += gridDim.x * 256){
    int j = i & 7, lane = (i >> 3) & 63, f = (i >> 9) & 15, ch = (i >> 13) & 7, l = i >> 16;
    int lr = lane & 15, lk = lane >> 4;
    int ks = f >> 3, nt = f & 7;
    int k = ch * 64 + ks * 32 + lk * 8 + j, n = nt * 16 + lr;
    float v = in[(size_t)l * 65536 + (size_t)k * 128 + n];
    *(__hip_bfloat16*)(img + (size_t)(l * 8 + ch) * 16384 + f * 1024 + lane * 16 + j * 2) =
        __float2bfloat16(v);
  }
}

// ---------- fused cell embed + LN1 ----------
__global__ __launch_bounds__(256) void embed_ln_k(const float* __restrict__ x,
    const float* __restrict__ W, const float* __restrict__ b,
    const float* __restrict__ g, const float* __restrict__ lb,
    float* __restrict__ h, __hip_bfloat16* __restrict__ xn, int M)
{
  int lane = threadIdx.x & 63, wid = threadIdx.x >> 6;
  float w0[32], w1[32];
  #pragma unroll
  for (int k = 0; k < 32; k++){
    w0[k] = W[k * 128 + lane];
    w1[k] = W[k * 128 + 64 + lane];
  }
  float b0 = b[lane], b1 = b[lane + 64];
  float g0 = g[lane], g1 = g[lane + 64];
  float e0 = lb[lane], e1 = lb[lane + 64];
  for (int n = blockIdx.x * 4 + wid; n < M; n += gridDim.x * 4){
    const float4* xr = (const float4*)(x + (size_t)n * 32);
    float xs[32];
    #pragma unroll
    for (int q = 0; q < 8; q++){
      float4 t = xr[q];
      xs[4*q] = t.x; xs[4*q+1] = t.y; xs[4*q+2] = t.z; xs[4*q+3] = t.w;
    }
    float a0 = b0, a1 = b1;
    #pragma unroll
    for (int k = 0; k < 32; k++){ a0 += xs[k] * w0[k]; a1 += xs[k] * w1[k]; }
    h[(size_t)n * H + lane]      = a0;
    h[(size_t)n * H + lane + 64] = a1;
    float mu = wsum(a0 + a1) * (1.f / 128.f);
    float d0 = a0 - mu, d1 = a1 - mu;
    float var = wsum(d0 * d0 + d1 * d1) * (1.f / 128.f);
    float rs = rsqrtf(var + 1e-5f);
    xn[(size_t)n * H + lane]      = __float2bfloat16(d0 * rs * g0 + e0);
    xn[(size_t)n * H + lane + 64] = __float2bfloat16(d1 * rs * g1 + e1);
  }
}

// ---------- well embedding ----------
template<int K>
__global__ __launch_bounds__(256) void embed_k(const float* __restrict__ x,
    const float* __restrict__ W, const float* __restrict__ b,
    float* __restrict__ h, int M)
{
  __shared__ float sW[K * 128];
  for (int t = threadIdx.x; t < K * 128; t += 256) sW[t] = W[t];
  __syncthreads();
  int j = threadIdx.x & 127, half = threadIdx.x >> 7;
  float bj = b[j];
  for (int n = blockIdx.x * 2 + half; n < M; n += gridDim.x * 2){
    const float* xr = x + (size_t)n * K;
    float acc = bj;
    #pragma unroll
    for (int k = 0; k < K; k++) acc += xr[k] * sW[k * 128 + j];
    h[(size_t)n * H + j] = acc;
  }
}

// ---------- per-layer scalar edge coefficients ----------
__global__ void coeff_k(const float* __restrict__ gWe, const float* __restrict__ gae,
    const float* __restrict__ Wee, const float* __restrict__ bee, float* __restrict__ coeff)
{
  __shared__ float red[4];
  int t = threadIdx.x;
  for (int i = 0; i < NL; i++){
    const float* Wr = gWe + ((size_t)i * H + t) * H;
    const float* ga = gae + (size_t)i * H;
    float w = 0.f;
    for (int k = 0; k < H; k++) w += Wr[k] * ga[k];
    float pc = Wee[t] * w, pd = bee[t] * w;
    pc = wsum(pc); pd = wsum(pd);
    if ((t & 63) == 0){ red[(t >> 6) * 2 + 0] = pc; red[(t >> 6) * 2 + 1] = pd; }
    __syncthreads();
    if (t == 0){ coeff[i] = red[0] + red[2]; coeff[NL + i] = red[1] + red[3]; }
    __syncthreads();
  }
}

// ---------- dot product per node (wells only) ----------
__global__ __launch_bounds__(256) void dot2_k(const float* __restrict__ X,
    const float* __restrict__ va, float* __restrict__ oa, int M)
{
  int lane = threadIdx.x & 63, wid = threadIdx.x >> 6;
  int n = blockIdx.x * 4 + wid;
  if (n >= M) return;
  const float* row = X + (size_t)n * H;
  float a = wsum(row[lane] * va[lane] + row[lane + 64] * va[lane + 64]);
  if (lane == 0) oa[n] = a;
}

// ---------- MFMA GEMM (layer 0): A in regs, frag-major W image -> LDS ----------
__global__ __launch_bounds__(512, 4) void gemm_mfma_k(
    const __hip_bfloat16* __restrict__ A, const char* __restrict__ Wimg,
    __hip_bfloat16* __restrict__ Cbf,
    const float* __restrict__ va, const float* __restrict__ vb,
    float* __restrict__ oa, float* __restrict__ ob, int M)
{
  __shared__ uint4 sW4[2048];
  char* sW = (char*)sW4;
  const int tid = threadIdx.x;
  const int lane = tid & 63, w = tid >> 6;
  const int n0 = blockIdx.x * 128;
  const int rw = w * 16;
  const int lr = lane & 15, lk = lane >> 4;

  {
    int go = w * 1024 + lane * 16;
    #pragma unroll
    for (int q = 0; q < 4; q++)
      gload16(Wimg + q * 8192 + go, sW + q * 8192 + w * 1024);
  }

  const int arow = n0 + rw + lr;
  bf16x8 aX[4];
  if (arow < M){
    #pragma unroll
    for (int ks = 0; ks < 4; ks++)
      aX[ks] = *(const bf16x8*)(A + (size_t)arow * 128 + ks * 32 + lk * 8);
  } else {
    #pragma unroll
    for (int ks = 0; ks < 4; ks++) aX[ks] = (bf16x8){0,0,0,0,0,0,0,0};
  }
  __syncthreads();

  f32x4 acc[8];
  #pragma unroll
  for (int i = 0; i < 8; i++) acc[i] = (f32x4){0.f, 0.f, 0.f, 0.f};
  #pragma unroll
  for (int ks = 0; ks < 4; ks++){
    #pragma unroll
    for (int nt = 0; nt < 8; nt++){
      bf16x8 b = *(const bf16x8*)(sW + ((ks << 3) + nt) * 1024 + (lane << 4));
      acc[nt] = MFMA16(aX[ks], b, acc[nt]);
    }
  }
  #pragma unroll
  for (int nt = 0; nt < 8; nt++){
    int col = nt * 16 + lr;
    #pragma unroll
    for (int r = 0; r < 4; r++){
      int row = n0 + rw + lk * 4 + r;
      if (row < M) Cbf[(size_t)row * 128 + col] = __float2bfloat16(acc[nt][r]);
    }
  }
  {
    float vac[8], vbc[8];
    #pragma unroll
    for (int nt = 0; nt < 8; nt++){
      vac[nt] = va[nt * 16 + lr];
      vbc[nt] = vb ? vb[nt * 16 + lr] : 0.f;
    }
    #pragma unroll
    for (int r = 0; r < 4; r++){
      float da = 0.f, db = 0.f;
      #pragma unroll
      for (int nt = 0; nt < 8; nt++){
        da += acc[nt][r] * vac[nt];
        db += acc[nt][r] * vbc[nt];
      }
      #pragma unroll
      for (int o = 1; o < 16; o <<= 1){
        da += __shfl_xor(da, o, 64);
        db += __shfl_xor(db, o, 64);
      }
      int row = n0 + rw + lk * 4 + r;
      if (lr == 0 && row < M){
        oa[row] = da;
        if (ob) ob[row] = db;
      }
    }
  }
}

// ---------- MEGA: GAT(i) + FFN(i) + GEMM(i+1), pipelined phase A ----------
__global__ __launch_bounds__(512, 4) void mega_k(
    const int* __restrict__ incl, const int* __restrict__ csr,
    const int* __restrict__ src, const float* __restrict__ attr,
    const float* __restrict__ coeff, int ci,
    const float* __restrict__ as_in, const float* __restrict__ ad_in,
    const __hip_bfloat16* __restrict__ X,
    const float* __restrict__ gbv,
    const float* __restrict__ n2gv, const float* __restrict__ n2bv,
    float* __restrict__ h,
    const char* __restrict__ W1img, const float* __restrict__ b1,
    const char* __restrict__ W2img, const float* __restrict__ b2,
    const float* __restrict__ lng, const float* __restrict__ lnb,
    const char* __restrict__ Wg,
    const float* __restrict__ va, const float* __restrict__ vb,
    float* __restrict__ oa, float* __restrict__ ob,
    __hip_bfloat16* __restrict__ Cbf, int mode, int M)
{
  __shared__ uint4 sW1_4[2][1024];
  __shared__ uint4 sW2_4[2][1024];
  __shared__ uint4 sT4[1024];
  char* sT = (char*)sT4;
  const int tid = threadIdx.x;
  const int lane = tid & 63, w = tid >> 6;
  const int n0 = blockIdx.x * 128;
  const int rw = w * 16;
  const int lr = lane & 15, lk = lane >> 4;
  const int gl = lane & 15, grp = lane >> 4;
  const int go = w * 1024 + lane * 16;
  const int lo = w * 1024;
  char* sTw = sT + w * 2048;
  char* aimgW = (w < 4) ? ((char*)sW1_4[1] + w * 4096)
                        : ((char*)sW2_4[1] + (w - 4) * 4096);

  gload16(W1img + go,        (char*)sW1_4[0] + lo);
  gload16(W1img + 8192 + go, (char*)sW1_4[0] + 8192 + lo);
  gload16(W2img + go,        (char*)sW2_4[0] + lo);
  gload16(W2img + 8192 + go, (char*)sW2_4[0] + 8192 + lo);

  const float c0 = coeff[ci], c1 = coeff[NL + ci];
  const int gbase = grp << 4;
  const int nb = n0 + w * 16 + grp * 4;

#define GACC2(A, U, P) \
    A[0] += (P) * __uint_as_float((U).x << 16); \
    A[1] += (P) * __uint_as_float((U).x & 0xffff0000u); \
    A[2] += (P) * __uint_as_float((U).y << 16); \
    A[3] += (P) * __uint_as_float((U).y & 0xffff0000u); \
    A[4] += (P) * __uint_as_float((U).z << 16); \
    A[5] += (P) * __uint_as_float((U).z & 0xffff0000u); \
    A[6] += (P) * __uint_as_float((U).w << 16); \
    A[7] += (P) * __uint_as_float((U).w & 0xffff0000u);

// epilogue for one node: hv = h + msg + gb; h store; LN -> A-image
#define NODE_EPI(Q, ACC) { \
    int n = nb + (Q); \
    char* adst = aimgW + ((gl >> 2) << 10) + ((((gl & 3) << 4) + grp * 4 + (Q)) << 4); \
    if (n >= M){ *(uint4*)adst = make_uint4(0u,0u,0u,0u); } else { \
      float inv = (s4[Q] == 0.f) ? 0.f : 1.f / s4[Q]; \
      int j0 = gl * 8; \
      float4 h0 = *(float4*)&h[(size_t)n * H + j0]; \
      float4 h1 = *(float4*)&h[(size_t)n * H + j0 + 4]; \
      float4 g0 = *(const float4*)&gbv[j0]; \
      float4 g1 = *(const float4*)&gbv[j0 + 4]; \
      float hv[8]; \
      hv[0] = h0.x + ACC[0]*inv + g0.x; hv[1] = h0.y + ACC[1]*inv + g0.y; \
      hv[2] = h0.z + ACC[2]*inv + g0.z; hv[3] = h0.w + ACC[3]*inv + g0.w; \
      hv[4] = h1.x + ACC[4]*inv + g1.x; hv[5] = h1.y + ACC[5]*inv + g1.y; \
      hv[6] = h1.z + ACC[6]*inv + g1.z; hv[7] = h1.w + ACC[7]*inv + g1.w; \
      float ls = 0.f; \
      _Pragma("unroll") for (int i = 0; i < 8; i++) ls += hv[i]; \
      float mu = gsum16(ls) * (1.f / H); \
      float vs = 0.f; \
      _Pragma("unroll") for (int i = 0; i < 8; i++){ float d = hv[i]-mu; vs += d*d; } \
      float var = gsum16(vs) * (1.f / H); \
      float rsq = rsqrtf(var + 1e-5f); \
      float4 o0, o1; \
      o0.x=hv[0]; o0.y=hv[1]; o0.z=hv[2]; o0.w=hv[3]; \
      o1.x=hv[4]; o1.y=hv[5]; o1.z=hv[6]; o1.w=hv[7]; \
      *(float4*)&h[(size_t)n * H + j0] = o0; \
      *(float4*)&h[(size_t)n * H + j0 + 4] = o1; \
      float4 gg0 = *(const float4*)&n2gv[j0]; \
      float4 gg1 = *(const float4*)&n2gv[j0 + 4]; \
      float4 bb0 = *(const float4*)&n2bv[j0]; \
      float4 bb1 = *(const float4*)&n2bv[j0 + 4]; \
      float xo[8]; \
      xo[0]=(hv[0]-mu)*rsq*gg0.x+bb0.x; xo[1]=(hv[1]-mu)*rsq*gg0.y+bb0.y; \
      xo[2]=(hv[2]-mu)*rsq*gg0.z+bb0.z; xo[3]=(hv[3]-mu)*rsq*gg0.w+bb0.w; \
      xo[4]=(hv[4]-mu)*rsq*gg1.x+bb1.x; xo[5]=(hv[5]-mu)*rsq*gg1.y+bb1.y; \
      xo[6]=(hv[6]-mu)*rsq*gg1.z+bb1.z; xo[7]=(hv[7]-mu)*rsq*gg1.w+bb1.w; \
      uint4 ow; unsigned* owp = (unsigned*)&ow; \
      _Pragma("unroll") for (int i = 0; i < 4; i++){ \
        __hip_bfloat16 lo2 = __float2bfloat16(xo[2*i]); \
        __hip_bfloat16 hi2 = __float2bfloat16(xo[2*i+1]); \
        owp[i] = ((unsigned)(*(unsigned short*)&hi2) << 16) | (*(unsigned short*)&lo2); \
      } \
      *(uint4*)adst = ow; \
    } }

  // ---- phase A ----
  int beg4[4], cnt4[4];
  #pragma unroll
  for (int q = 0; q < 4; q++){
    int n = nb + q;
    if (n < M){
      int b0 = (n == 0) ? 0 : incl[n - 1];
      beg4[q] = b0;
      cnt4[q] = incl[n] - b0;
    } else { beg4[q] = 0; cnt4[q] = 0; }
  }
  bool big = (cnt4[0] > 16) || (cnt4[1] > 16) || (cnt4[2] > 16) || (cnt4[3] > 16);

  if (!__any(big)){
    // FAST PATH: deg<=16 everywhere in this wave; pipeline the pointer chases
    float adn4[4];
    #pragma unroll
    for (int q = 0; q < 4; q++) adn4[q] = (nb + q < M) ? ad_in[nb + q] : 0.f;
    int e4[4];
    #pragma unroll
    for (int q = 0; q < 4; q++) e4[q] = (gl < cnt4[q]) ? csr[beg4[q] + gl] : 0;
    int sv4[4];
    #pragma unroll
    for (int q = 0; q < 4; q++) sv4[q] = (gl < cnt4[q]) ? src[e4[q]] : 0;
    float at4[4];
    #pragma unroll
    for (int q = 0; q < 4; q++) at4[q] = (gl < cnt4[q]) ? attr[e4[q]] : 0.f;
    float as4[4];
    #pragma unroll
    for (int q = 0; q < 4; q++) as4[q] = (gl < cnt4[q]) ? as_in[sv4[q]] : 0.f;
    float p4[4], s4[4];
    #pragma unroll
    for (int q = 0; q < 4; q++){
      bool v = gl < cnt4[q];
      float a = v ? (as4[q] + adn4[q] + at4[q] * c0 + c1) : -1e30f;
      a = (a > 0.f) ? a : 0.2f * a;
      float mq = gmax16(a);
      float p = v ? expf(a - mq) : 0.f;
      s4[q] = gsum16(p);
      p4[q] = p;
    }
    #pragma unroll
    for (int qp = 0; qp < 2; qp++){
      const int q0 = qp * 2, q1 = qp * 2 + 1;
      float accA[8], accB[8];
      #pragma unroll
      for (int i = 0; i < 8; i++){ accA[i] = 0.f; accB[i] = 0.f; }
      int cm = max(cnt4[q0], cnt4[q1]);
      for (int t = 0; t < cm; t += 2){
        float pa0 = __shfl(p4[q0], gbase + t, 64);
        float pb0 = __shfl(p4[q1], gbase + t, 64);
        float pa1 = __shfl(p4[q0], gbase + t + 1, 64);
        float pb1 = __shfl(p4[q1], gbase + t + 1, 64);
        int sa0 = __shfl(sv4[q0], gbase + t, 64);
        int sb0 = __shfl(sv4[q1], gbase + t, 64);
        int sa1 = __shfl(sv4[q0], gbase + t + 1, 64);
        int sb1 = __shfl(sv4[q1], gbase + t + 1, 64);
        uint4 ua0 = *(const uint4*)(X + (size_t)sa0 * H + gl * 8);
        uint4 ub0 = *(const uint4*)(X + (size_t)sb0 * H + gl * 8);
        uint4 ua1 = *(const uint4*)(X + (size_t)sa1 * H + gl * 8);
        uint4 ub1 = *(const uint4*)(X + (size_t)sb1 * H + gl * 8);
        GACC2(accA, ua0, pa0) GACC2(accB, ub0, pb0)
        GACC2(accA, ua1, pa1) GACC2(accB, ub1, pb1)
      }
      NODE_EPI(q0, accA)
      NODE_EPI(q1, accB)
    }
  } else {
    // SLOW PATH (rare): original serial per-node online-softmax loop
    for (int q = 0; q < 4; q++){
      int n = nb + q;
      char* adst = aimgW + ((gl >> 2) << 10) + ((((gl & 3) << 4) + grp * 4 + q) << 4);
      if (n >= M){ *(uint4*)adst = make_uint4(0u,0u,0u,0u); continue; }
      int beg = beg4[q];
      int end = beg4[q] + cnt4[q];
      float adn = ad_in[n];
      float m = -1e30f, s = 0.f;
      float acc[8];
      #pragma unroll
      for (int i = 0; i < 8; i++) acc[i] = 0.f;
      for (int base = beg; base < end; base += 16){
        int idx = base + gl;
        bool valid = idx < end;
        int e = valid ? csr[idx] : 0;
        int sv = valid ? src[e] : 0;
        float a = -1e30f;
        if (valid){
          a = as_in[sv] + adn + attr[e] * c0 + c1;
          a = (a > 0.f) ? a : 0.2f * a;
        }
        float cmx = gmax16(a);
        float nm = fmaxf(m, cmx);
        float sc = expf(m - nm);
        #pragma unroll
        for (int i = 0; i < 8; i++) acc[i] *= sc;
        s *= sc;
        float p = valid ? expf(a - nm) : 0.f;
        s += gsum16(p);
        m = nm;
        int cnt = min(16, end - base);
        for (int t = 0; t < cnt; t++){
          float pt = __shfl(p, gbase + t, 64);
          int st = __shfl(sv, gbase + t, 64);
          uint4 u = *(const uint4*)(X + (size_t)st * H + gl * 8);
          GACC2(acc, u, pt)
        }
      }
      float s4q = s;
      float s4[4]; s4[q] = s4q;   // reuse NODE_EPI shape
      NODE_EPI(q, acc)
    }
  }
#undef GACC2

  // A-image complete for this wave -> load aX fragments
  asm volatile("s_waitcnt lgkmcnt(0)" ::: "memory");
  bf16x8 aX[4];
  #pragma unroll
  for (int ks = 0; ks < 4; ks++)
    aX[ks] = *(const bf16x8*)(aimgW + (ks << 10) + (lane << 4));
  asm volatile("s_waitcnt lgkmcnt(0) vmcnt(0)" ::: "memory");
  __builtin_amdgcn_s_barrier();

  f32x4 acc2[8];
  #pragma unroll
  for (int i = 0; i < 8; i++) acc2[i] = (f32x4){0.f, 0.f, 0.f, 0.f};

  const int rdA = ((lane ^ ((lane >> 3) & 7)) << 4);

  for (int ch = 0; ch < DFF / DC; ch++){
    const int cur = ch & 1;
    if (ch < DFF / DC - 1){
      const char* g1 = W1img + (size_t)(ch + 1) * 16384;
      const char* g2 = W2img + (size_t)(ch + 1) * 16384;
      char* d1 = (char*)sW1_4[cur ^ 1];
      char* d2 = (char*)sW2_4[cur ^ 1];
      gload16(g1 + go,        d1 + lo);
      gload16(g1 + 8192 + go, d1 + 8192 + lo);
      gload16(g2 + go,        d2 + lo);
      gload16(g2 + 8192 + go, d2 + 8192 + lo);
    } else {
      gload16(Wg + go,         (char*)sW1_4[0] + lo);
      gload16(Wg + 8192 + go,  (char*)sW1_4[0] + 8192 + lo);
      gload16(Wg + 16384 + go, (char*)sW2_4[0] + lo);
      gload16(Wg + 24576 + go, (char*)sW2_4[0] + 8192 + lo);
    }

    const char* W1c = (const char*)sW1_4[cur];
    const char* W2c = (const char*)sW2_4[cur];

    f32x4 acc1[4];
    #pragma unroll
    for (int i = 0; i < 4; i++) acc1[i] = (f32x4){0.f, 0.f, 0.f, 0.f};
    #pragma unroll
    for (int ks = 0; ks < 4; ks++){
      #pragma unroll
      for (int nt = 0; nt < 4; nt++){
        bf16x8 b = *(const bf16x8*)(W1c + ((ks << 2) + nt) * 1024 + (lane << 4));
        acc1[nt] = MFMA16(aX[ks], b, acc1[nt]);
      }
    }
    #pragma unroll
    for (int nt = 0; nt < 4; nt++){
      int col = nt * 16 + lr;
      float bb = b1[ch * DC + col];
      int ksp = col >> 5;
      int qhi = ((col >> 3) & 3) << 4;
      int jb  = (col & 7) << 1;
      #pragma unroll
      for (int r = 0; r < 4; r++){
        int slot = qhi + lk * 4 + r;
        int slotp = slot ^ ((slot >> 3) & 7);
        float v = fmaxf(acc1[nt][r] + bb, 0.f);
        *(__hip_bfloat16*)(sTw + (ksp << 10) + (slotp << 4) + jb) = __float2bfloat16(v);
      }
    }
    asm volatile("s_waitcnt lgkmcnt(0)" ::: "memory");

    #pragma unroll
    for (int ks = 0; ks < 2; ks++){
      bf16x8 a = *(const bf16x8*)(sTw + (ks << 10) + rdA);
      #pragma unroll
      for (int nt = 0; nt < 8; nt++){
        bf16x8 b = *(const bf16x8*)(W2c + ((ks << 3) + nt) * 1024 + (lane << 4));
        acc2[nt] = MFMA16(a, b, acc2[nt]);
      }
    }
    if (ch < DFF / DC - 1){
      asm volatile("s_waitcnt vmcnt(0)" ::: "memory");
      __builtin_amdgcn_s_barrier();
    }
  }

  asm volatile("s_waitcnt vmcnt(0)" ::: "memory");
  __builtin_amdgcn_s_barrier();

  float b2c[8];
  #pragma unroll
  for (int nt = 0; nt < 8; nt++) b2c[nt] = b2[nt * 16 + lr];
  float lngc[8], lnbc[8];
  if (mode == 0){
    #pragma unroll
    for (int nt = 0; nt < 8; nt++){
      lngc[nt] = lng[nt * 16 + lr];
      lnbc[nt] = lnb[nt * 16 + lr];
    }
  }

  #pragma unroll
  for (int r = 0; r < 4; r++){
    int row = n0 + rw + lk * 4 + r;
    bool ok = row < M;
    float val[8]; float sum = 0.f;
    #pragma unroll
    for (int nt = 0; nt < 8; nt++){
      int col = nt * 16 + lr;
      float hv = ok ? h[(size_t)row * 128 + col] : 0.f;
      val[nt] = hv + acc2[nt][r] + b2c[nt];
      sum += val[nt];
    }
    float mu = 0.f, rs = 1.f;
    if (mode == 0){
      #pragma unroll
      for (int o = 1; o < 16; o <<= 1) sum += __shfl_xor(sum, o, 64);
      mu = sum * (1.f / 128.f);
      float vs = 0.f;
      #pragma unroll
      for (int nt = 0; nt < 8; nt++){ float d = val[nt] - mu; vs += d * d; }
      #pragma unroll
      for (int o = 1; o < 16; o <<= 1) vs += __shfl_xor(vs, o, 64);
      rs = rsqrtf(vs * (1.f / 128.f) + 1e-5f);
    }
    #pragma unroll
    for (int nt = 0; nt < 8; nt++){
      int col = nt * 16 + lr;
      if (mode == 0 && ok) h[(size_t)row * 128 + col] = val[nt];
      float xo = (mode == 0) ? ((val[nt] - mu) * rs * lngc[nt] + lnbc[nt]) : val[nt];
      int lanep = ((((nt & 1) << 1) + (lr >> 3)) << 4) + (lk << 2) + r;
      *(__hip_bfloat16*)(aimgW + ((nt >> 1) << 10) + (lanep << 4) + ((lr & 7) << 1)) =
          __float2bfloat16(xo);
    }
  }
  asm volatile("s_waitcnt lgkmcnt(0)" ::: "memory");

  bf16x8 aG[4];
  #pragma unroll
  for (int ks = 0; ks < 4; ks++)
    aG[ks] = *(const bf16x8*)(aimgW + (ks << 10) + (lane << 4));
  f32x4 accG[8];
  #pragma unroll
  for (int i = 0; i < 8; i++) accG[i] = (f32x4){0.f, 0.f, 0.f, 0.f};
  #pragma unroll
  for (int ks = 0; ks < 4; ks++){
    #pragma unroll
    for (int nt = 0; nt < 8; nt++){
      const char* bptr = (ks < 2)
          ? ((const char*)sW1_4[0] + (((ks << 3) + nt) << 10) + (lane << 4))
          : ((const char*)sW2_4[0] + ((((ks - 2) << 3) + nt) << 10) + (lane << 4));
      accG[nt] = MFMA16(aG[ks], *(const bf16x8*)bptr, accG[nt]);
    }
  }
  #pragma unroll
  for (int nt = 0; nt < 8; nt++){
    int col = nt * 16 + lr;
    #pragma unroll
    for (int r = 0; r < 4; r++){
      int row = n0 + rw + lk * 4 + r;
      if (row < M) Cbf[(size_t)row * 128 + col] = __float2bfloat16(accG[nt][r]);
    }
  }
  {
    float vac[8], vbc[8];
    #pragma unroll
    for (int nt = 0; nt < 8; nt++){
      vac[nt] = va[nt * 16 + lr];
      vbc[nt] = vb ? vb[nt * 16 + lr] : 0.f;
    }
    #pragma unroll
    for (int r = 0; r < 4; r++){
      float da = 0.f, db = 0.f;
      #pragma unroll
      for (int nt = 0; nt < 8; nt++){
        da += accG[nt][r] * vac[nt];
        db += accG[nt][r] * vbc[nt];
      }
      #pragma unroll
      for (int o = 1; o < 16; o <<= 1){
        da += __shfl_xor(da, o, 64);
        db += __shfl_xor(db, o, 64);
      }
      int row = n0 + rw + lk * 4 + r;
      if (lr == 0 && row < M){
        oa[row] = da;
        if (ob) ob[row] = db;
      }
    }
  }
#undef NODE_EPI
}

// ---------- fp32 GEMM (tiny well matmul) ----------
__global__ __launch_bounds__(256) void gemm128_k(const float* __restrict__ A,
    const float* __restrict__ Bm, float* __restrict__ C, int M)
{
  __shared__ float sB[32 * 128];
  __shared__ float sA[64 * 33];
  const int tid = threadIdx.x;
  const int n0 = blockIdx.x * 64;
  const int j4 = (tid & 31) * 4;
  const int rB = (tid >> 5) * 8;
  float acc[8][4];
  #pragma unroll
  for (int r = 0; r < 8; r++){ acc[r][0]=acc[r][1]=acc[r][2]=acc[r][3]=0.f; }
  for (int kc = 0; kc < 128; kc += 32){
    for (int t = tid; t < 4096; t += 256){
      int kk = t >> 7, j = t & 127;
      sB[kk * 128 + j] = Bm[(size_t)(kc + kk) * H + j];
    }
    for (int t = tid; t < 2048; t += 256){
      int n = t >> 5, kk = t & 31; int row = n0 + n;
      sA[n * 33 + kk] = (row < M) ? A[(size_t)row * H + kc + kk] : 0.f;
    }
    __syncthreads();
    #pragma unroll 8
    for (int kk = 0; kk < 32; kk++){
      float4 bv = *(const float4*)&sB[kk * 128 + j4];
      #pragma unroll
      for (int r = 0; r < 8; r++){
        float av = sA[(rB + r) * 33 + kk];
        acc[r][0] += av * bv.x; acc[r][1] += av * bv.y;
        acc[r][2] += av * bv.z; acc[r][3] += av * bv.w;
      }
    }
    __syncthreads();
  }
  #pragma unroll
  for (int r = 0; r < 8; r++){
    int row = n0 + rB + r;
    if (row < M){
      float4 o; o.x = acc[r][0]; o.y = acc[r][1]; o.z = acc[r][2]; o.w = acc[r][3];
      *(float4*)&C[(size_t)row * H + j4] = o;
    }
  }
}

// ---------- CSR build ----------
__global__ void count_k(const int* __restrict__ dst, int* __restrict__ cnt, int NE){
  int e = blockIdx.x * 256 + threadIdx.x;
  if (e < NE) atomicAdd(&cnt[dst[e]], 1);
}
__global__ void scan1_k(const int* __restrict__ in, int* __restrict__ out,
                        int* __restrict__ bsum, int N){
  __shared__ int sd[256];
  int tid = threadIdx.x;
  int base = blockIdx.x * 1024 + tid * 4;
  int v0 = (base + 0 < N) ? in[base + 0] : 0;
  int v1 = (base + 1 < N) ? in[base + 1] : 0;
  int v2 = (base + 2 < N) ? in[base + 2] : 0;
  int v3 = (base + 3 < N) ? in[base + 3] : 0;
  sd[tid] = v0 + v1 + v2 + v3;
  __syncthreads();
  for (int off = 1; off < 256; off <<= 1){
    int t = (tid >= off) ? sd[tid - off] : 0;
    __syncthreads();
    sd[tid] += t;
    __syncthreads();
  }
  int run = (tid > 0) ? sd[tid - 1] : 0;
  run += v0; if (base + 0 < N) out[base + 0] = run;
  run += v1; if (base + 1 < N) out[base + 1] = run;
  run += v2; if (base + 2 < N) out[base + 2] = run;
  run += v3; if (base + 3 < N) out[base + 3] = run;
  if (tid == 255) bsum[blockIdx.x] = sd[255];
}
__global__ void scan2_k(int* __restrict__ bs, int NB){
  __shared__ int sd[256];
  int tid = threadIdx.x;
  int base = tid * 4;
  int v0 = (base + 0 < NB) ? bs[base + 0] : 0;
  int v1 = (base + 1 < NB) ? bs[base + 1] : 0;
  int v2 = (base + 2 < NB) ? bs[base + 2] : 0;
  int v3 = (base + 3 < NB) ? bs[base + 3] : 0;
  sd[tid] = v0 + v1 + v2 + v3;
  __syncthreads();
  for (int off = 1; off < 256; off <<= 1){
    int t = (tid >= off) ? sd[tid - off] : 0;
    __syncthreads();
    sd[tid] += t;
    __syncthreads();
  }
  int run = (tid > 0) ? sd[tid - 1] : 0;
  run += v0; if (base + 0 < NB) bs[base + 0] = run;
  run += v1; if (base + 1 < NB) bs[base + 1] = run;
  run += v2; if (base + 2 < NB) bs[base + 2] = run;
  run += v3; if (base + 3 < NB) bs[base + 3] = run;
}
__global__ void scan3_k(int* __restrict__ out, const int* __restrict__ bsum, int N){
  int b = blockIdx.x;
  if (b == 0) return;
  int add = bsum[b - 1];
  int i = b * 1024 + threadIdx.x * 4;
  #pragma unroll
  for (int j = 0; j < 4; j++) if (i + j < N) out[i + j] += add;
}
__global__ void initfill_k(const int* __restrict__ incl, int* __restrict__ fill, int N){
  int i = blockIdx.x * 256 + threadIdx.x;
  if (i < N) fill[i] = (i == 0) ? 0 : incl[i - 1];
}
__global__ void fill_k(const int* __restrict__ dst, int* __restrict__ fill,
                       int* __restrict__ csr, int NE){
  int e = blockIdx.x * 256 + threadIdx.x;
  if (e < NE){
    int p = atomicAdd(&fill[dst[e]], 1);
    csr[p] = e;
  }
}

// ---------- standalone GAT gather (wells only, no residual) ----------
__global__ __launch_bounds__(256) void gat_k(
    const int* __restrict__ incl, const int* __restrict__ csr,
    const int* __restrict__ src,
    const float* __restrict__ as_, const float* __restrict__ ad_,
    const __hip_bfloat16* __restrict__ X, float* __restrict__ hout, int M)
{
  int lane = threadIdx.x & 63, wid = threadIdx.x >> 6;
  int grp = lane >> 4, gl = lane & 15;
  int n = blockIdx.x * 16 + wid * 4 + grp;
  if (n >= M) return;
  int beg = (n == 0) ? 0 : incl[n - 1];
  int end = incl[n];
  float adn = ad_[n];
  const int gbase = grp << 4;
  float m = -1e30f, s = 0.f;
  float acc[8];
  #pragma unroll
  for (int i = 0; i < 8; i++) acc[i] = 0.f;
#define GACC(U, P) \
    acc[0] += (P) * __uint_as_float((U).x << 16); \
    acc[1] += (P) * __uint_as_float((U).x & 0xffff0000u); \
    acc[2] += (P) * __uint_as_float((U).y << 16); \
    acc[3] += (P) * __uint_as_float((U).y & 0xffff0000u); \
    acc[4] += (P) * __uint_as_float((U).z << 16); \
    acc[5] += (P) * __uint_as_float((U).z & 0xffff0000u); \
    acc[6] += (P) * __uint_as_float((U).w << 16); \
    acc[7] += (P) * __uint_as_float((U).w & 0xffff0000u);
  for (int base = beg; base < end; base += 16){
    int idx = base + gl;
    bool valid = idx < end;
    int e = valid ? csr[idx] : 0;
    int sv = valid ? src[e] : 0;
    float a = -1e30f;
    if (valid){
      a = as_[sv] + adn;
      a = (a > 0.f) ? a : 0.2f * a;
    }
    float cm = gmax16(a);
    float nm = fmaxf(m, cm);
    float sc = expf(m - nm);
    #pragma unroll
    for (int i = 0; i < 8; i++) acc[i] *= sc;
    s *= sc;
    float p = valid ? expf(a - nm) : 0.f;
    s += gsum16(p);
    m = nm;
    int cnt = min(16, end - base);
    for (int t = 0; t < cnt; t++){
      float pt = __shfl(p, gbase + t, 64);
      int st = __shfl(sv, gbase + t, 64);
      uint4 u = *(const uint4*)(X + (size_t)st * H + gl * 8);
      GACC(u, pt)
    }
  }
#undef GACC
  float inv = (s == 0.f) ? 0.f : 1.f / s;
  int j0 = gl * 8;
  float4 o0, o1;
  o0.x = acc[0]*inv; o0.y = acc[1]*inv; o0.z = acc[2]*inv; o0.w = acc[3]*inv;
  o1.x = acc[4]*inv; o1.y = acc[5]*inv; o1.z = acc[6]*inv; o1.w = acc[7]*inv;
  *(float4*)&hout[(size_t)n * H + j0] = o0;
  *(float4*)&hout[(size_t)n * H + j0 + 4] = o1;
}

// ---------- final well MLP ----------
__global__ __launch_bounds__(128) void mlp_k(const float* __restrict__ hwell,
    const float* __restrict__ wb, const float* __restrict__ mW1,
    const float* __restrict__ mb1, const float* __restrict__ mW2,
    const float* __restrict__ mb2, float* __restrict__ out)
{
  __shared__ float sH[128], sT[128];
  int n = blockIdx.x, j = threadIdx.x;
  sH[j] = hwell[(size_t)n * H + j] + wb[j];
  __syncthreads();
  float a = mb1[j];
  for (int k = 0; k < 128; k++) a += sH[k] * mW1[k * 128 + j];
  sT[j] = fmaxf(a, 0.f);
  __syncthreads();
  if (j < 75){
    float o = mb2[j];
    for (int k = 0; k < 128; k++) o += sT[k] * mW2[k * 75 + j];
    out[(size_t)n * 75 + j] = o;
  }
}

extern "C" void kernel_launch(void* const* d_in, const int* in_sizes, int n_in,
                              void* d_out, int out_size, void* d_ws, size_t ws_size,
                              hipStream_t stream)
{
  (void)in_sizes; (void)n_in; (void)out_size; (void)ws_size;
  const float* cell_x = (const float*)d_in[0];
  const float* well_x = (const float*)d_in[1];
  const int*   eidx   = (const int*)d_in[2];
  const float* eattr  = (const float*)d_in[3];
  const int*   wsrc   = (const int*)d_in[4];
  const int*   wdst   = (const int*)d_in[5];
  const float* W_cell = (const float*)d_in[6];
  const float* b_cell = (const float*)d_in[7];
  const float* W_well = (const float*)d_in[8];
  const float* b_well = (const float*)d_in[9];
  const float* W_ee   = (const float*)d_in[10];
  const float* b_ee   = (const float*)d_in[11];
  const float* gW     = (const float*)d_in[12];
  const float* gas    = (const float*)d_in[13];
  const float* gad    = (const float*)d_in[14];
  const float* gae    = (const float*)d_in[15];
  const float* gWe    = (const float*)d_in[16];
  const float* gb     = (const float*)d_in[17];
  const float* n1g    = (const float*)d_in[18];
  const float* n1b    = (const float*)d_in[19];
  const float* fW1    = (const float*)d_in[20];
  const float* fb1    = (const float*)d_in[21];
  const float* fW2    = (const float*)d_in[22];
  const float* fb2    = (const float*)d_in[23];
  const float* n2g    = (const float*)d_in[24];
  const float* n2b    = (const float*)d_in[25];
  const float* wW     = (const float*)d_in[26];
  const float* was    = (const float*)d_in[27];
  const float* wad    = (const float*)d_in[28];
  const float* wb     = (const float*)d_in[29];
  const float* mW1    = (const float*)d_in[30];
  const float* mb1    = (const float*)d_in[31];
  const float* mW2    = (const float*)d_in[32];
  const float* mb2    = (const float*)d_in[33];

  const int* src = eidx;
  const int* dst = eidx + NE_CC;

  char* wsb = (char*)d_ws;
  size_t off = 0;
  auto alloc = [&](size_t bytes) -> void* {
    void* p = wsb + off; off += (bytes + 255) & ~(size_t)255; return p;
  };
  float* h      = (float*)alloc((size_t)NC * H * 4);
  __hip_bfloat16* xnbf  = (__hip_bfloat16*)alloc((size_t)NC * H * 2);
  __hip_bfloat16* hsbf0 = (__hip_bfloat16*)alloc((size_t)NC * H * 2);
  __hip_bfloat16* hsbf1 = (__hip_bfloat16*)alloc((size_t)NC * H * 2);
  float* as0    = (float*)alloc((size_t)NC * 4);
  float* ad0    = (float*)alloc((size_t)NC * 4);
  float* as1    = (float*)alloc((size_t)NC * 4);
  float* ad1    = (float*)alloc((size_t)NC * 4);
  float* hw     = (float*)alloc((size_t)NW * H * 4);
  float* hwp    = (float*)alloc((size_t)NW * H * 4);
  float* hwell  = (float*)alloc((size_t)NW * H * 4);
  float* coeff  = (float*)alloc(64);
  char* gWimg = (char*)alloc((size_t)NL * 32768);
  char* wWimg = (char*)alloc(32768);
  char* W1img = (char*)alloc((size_t)NL * 131072);
  char* W2img = (char*)alloc((size_t)NL * 131072);
  int* cntC  = (int*)alloc((size_t)NC * 4);
  int* inclC = (int*)alloc((size_t)NC * 4);
  int* fillC = (int*)alloc((size_t)NC * 4);
  int* csrC  = (int*)alloc((size_t)NE_CC * 4);
  int* inclW = (int*)alloc((size_t)NW * 4);
  int* fillW = (int*)alloc((size_t)NW * 4);
  int* csrW  = (int*)alloc((size_t)NE_CW * 4);
  int* bsum  = (int*)alloc(1024 * 4);

  const int eBlocks  = (NE_CC + 255) / 256;
  const int ewBlocks = (NE_CW + 255) / 256;
  const int NBC = (NC + 1023) / 1024;
  const int NBW = (NW + 1023) / 1024;

  // ---- CSR build (c2c) ----
  hipMemsetAsync(cntC, 0, (size_t)NC * 4, stream);
  count_k<<<eBlocks, 256, 0, stream>>>(dst, cntC, NE_CC);
  scan1_k<<<NBC, 256, 0, stream>>>(cntC, inclC, bsum, NC);
  scan2_k<<<1, 256, 0, stream>>>(bsum, NBC);
  scan3_k<<<NBC, 256, 0, stream>>>(inclC, bsum, NC);
  initfill_k<<<(NC + 255) / 256, 256, 0, stream>>>(inclC, fillC, NC);
  fill_k<<<eBlocks, 256, 0, stream>>>(dst, fillC, csrC, NE_CC);
  // ---- CSR build (c2w) ----
  hipMemsetAsync(fillW, 0, (size_t)NW * 4, stream);
  count_k<<<ewBlocks, 256, 0, stream>>>(wdst, fillW, NE_CW);
  scan1_k<<<NBW, 256, 0, stream>>>(fillW, inclW, bsum, NW);
  scan2_k<<<1, 256, 0, stream>>>(bsum, NBW);
  scan3_k<<<NBW, 256, 0, stream>>>(inclW, bsum, NW);
  initfill_k<<<(NW + 255) / 256, 256, 0, stream>>>(inclW, fillW, NW);
  fill_k<<<ewBlocks, 256, 0, stream>>>(wdst, fillW, csrW, NE_CW);

  // ---- weight image prep ----
  prep_imgGW_k<<<96, 256, 0, stream>>>(gW, gWimg, NL);
  prep_imgGW_k<<<32, 256, 0, stream>>>(wW, wWimg, 1);
  prep_imgW1_k<<<768, 256, 0, stream>>>(fW1, W1img);
  prep_imgW2_k<<<768, 256, 0, stream>>>(fW2, W2img);

  embed_ln_k<<<1024, 256, 0, stream>>>(cell_x, W_cell, b_cell, n1g, n1b, h, xnbf, NC);
  embed_k<16><<<250, 256, 0, stream>>>(well_x, W_well, b_well, hw, NW);
  coeff_k<<<1, 128, 0, stream>>>(gWe, gae, W_ee, b_ee, coeff);

  const int mfmaBlocks = (NC + 127) / 128;

  gemm_mfma_k<<<mfmaBlocks, 512, 0, stream>>>(xnbf, gWimg,
      hsbf0, gas, gad, as0, ad0, NC);

  for (int i = 0; i < NL; i++){
    const __hip_bfloat16* Xin = (i & 1) ? hsbf1 : hsbf0;
    __hip_bfloat16* Xout      = (i & 1) ? hsbf0 : hsbf1;
    const float* asi = (i & 1) ? as1 : as0;
    const float* adi = (i & 1) ? ad1 : ad0;
    float* aso = (i & 1) ? as0 : as1;
    float* ado = (i & 1) ? ad0 : ad1;
    if (i < NL - 1){
      mega_k<<<mfmaBlocks, 512, 0, stream>>>(inclC, csrC, src, eattr, coeff, i,
          asi, adi, Xin, gb + i * H, n2g + i * H, n2b + i * H, h,
          W1img + (size_t)i * 131072, fb1 + (size_t)i * DFF,
          W2img + (size_t)i * 131072, fb2 + (size_t)i * H,
          n1g + (i + 1) * H, n1b + (i + 1) * H,
          gWimg + (size_t)(i + 1) * 32768,
          gas + (i + 1) * H, gad + (i + 1) * H, aso, ado, Xout, 0, NC);
    } else {
      mega_k<<<mfmaBlocks, 512, 0, stream>>>(inclC, csrC, src, eattr, coeff, i,
          asi, adi, Xin, gb + i * H, n2g + i * H, n2b + i * H, h,
          W1img + (size_t)i * 131072, fb1 + (size_t)i * DFF,
          W2img + (size_t)i * 131072, fb2 + (size_t)i * H,
          n1g, n1b,
          wWimg, was, nullptr, aso, nullptr, Xout, 1, NC);
    }
  }

  gemm128_k<<<(NW + 63) / 64, 256, 0, stream>>>(hw, wW, hwp, NW);
  dot2_k<<<(NW + 3) / 4, 256, 0, stream>>>(hwp, wad, ad0, NW);
  gat_k<<<(NW + 15) / 16, 256, 0, stream>>>(inclW, csrW, wsrc,
      as1, ad0, hsbf1, hwell, NW);
  mlp_k<<<NW, 128, 0, stream>>>(hwell, wb, mW1, mb1, mW2, mb2, (float*)d_out);
}

// Round 22
// 539.229 us; speedup vs baseline: 1.3070x; 1.0835x over previous
//
#include <hip/hip_runtime.h>
#include <hip/hip_bf16.h>

#define NC 100000
#define NW 500
#define NE_CC 600000
#define NE_CW 25000
#define H 128
#define NL 3
#define DFF 512
#define DC 64

typedef __bf16 bf16x8 __attribute__((ext_vector_type(8)));
typedef float f32x4 __attribute__((ext_vector_type(4)));
#define MFMA16(a,b,c) __builtin_amdgcn_mfma_f32_16x16x32_bf16(a,b,c,0,0,0)

__device__ __forceinline__ float wsum(float v){
  #pragma unroll
  for (int o = 32; o; o >>= 1) v += __shfl_xor(v, o, 64);
  return v;
}
__device__ __forceinline__ float gsum16(float v){
  #pragma unroll
  for (int o = 1; o < 16; o <<= 1) v += __shfl_xor(v, o, 64);
  return v;
}
__device__ __forceinline__ float gmax16(float v){
  #pragma unroll
  for (int o = 1; o < 16; o <<= 1) v = fmaxf(v, __shfl_xor(v, o, 64));
  return v;
}

// async global->LDS, 16 B per lane; LDS dest = wave-uniform base + lane*16
__device__ __forceinline__ void gload16(const void* g, void* l){
  __builtin_amdgcn_global_load_lds(
      (const __attribute__((address_space(1))) void*)g,
      (__attribute__((address_space(3))) void*)l, 16, 0, 0);
}

// ======== fragment-major weight images ========
__global__ void prep_imgGW_k(const float* __restrict__ in, char* __restrict__ img, int nmat){
  int tot = nmat * 16384;
  for (int i = blockIdx.x * 256 + threadIdx.x; i < tot; i += gridDim.x * 256){
    int j = i & 7, lane = (i >> 3) & 63, f = (i >> 9) & 31, l = i >> 14;
    int lr = lane & 15, lk = lane >> 4;
    int ks = f >> 3, nt = f & 7;
    int k = ks * 32 + lk * 8 + j, n = nt * 16 + lr;
    float v = in[(size_t)l * 16384 + (size_t)k * 128 + n];
    *(__hip_bfloat16*)(img + (size_t)l * 32768 + f * 1024 + lane * 16 + j * 2) =
        __float2bfloat16(v);
  }
}
__global__ void prep_imgW1_k(const float* __restrict__ in, char* __restrict__ img){
  int tot = 3 * 65536;
  for (int i = blockIdx.x * 256 + threadIdx.x; i < tot; i += gridDim.x * 256){
    int j = i & 7, lane = (i >> 3) & 63, f = (i >> 9) & 15, ch = (i >> 13) & 7, l = i >> 16;
    int lr = lane & 15, lk = lane >> 4;
    int ks = f >> 2, nt = f & 3;
    int k = ks * 32 + lk * 8 + j, n = ch * 64 + nt * 16 + lr;
    float v = in[(size_t)l * 65536 + (size_t)k * 512 + n];
    *(__hip_bfloat16*)(img + (size_t)(l * 8 + ch) * 16384 + f * 1024 + lane * 16 + j * 2) =
        __float2bfloat16(v);
  }
}
__global__ void prep_imgW2_k(const float* __restrict__ in, char* __restrict__ img){
  int tot = 3 * 65536;
  for (int i = blockIdx.x * 256 + threadIdx.x; i < tot; i += gridDim.x * 256){
    int j = i & 7, lane = (i >> 3) & 63, f = (i >> 9) & 15, ch = (i >> 13) & 7, l = i >> 16;
    int lr = lane & 15, lk = lane >> 4;
    int ks = f >> 3, nt = f & 7;
    int k = ch * 64 + ks * 32 + lk * 8 + j, n = nt * 16 + lr;
    float v = in[(size_t)l * 65536 + (size_t)k * 128 + n];
    *(__hip_bfloat16*)(img + (size_t)(l * 8 + ch) * 16384 + f * 1024 + lane * 16 + j * 2) =
        __float2bfloat16(v);
  }
}

// ---------- fused cell embed + LN1 ----------
__global__ __launch_bounds__(256) void embed_ln_k(const float* __restrict__ x,
    const float* __restrict__ W, const float* __restrict__ b,
    const float* __restrict__ g, const float* __restrict__ lb,
    float* __restrict__ h, __hip_bfloat16* __restrict__ xn, int M)
{
  int lane = threadIdx.x & 63, wid = threadIdx.x >> 6;
  float w0[32], w1[32];
  #pragma unroll
  for (int k = 0; k < 32; k++){
    w0[k] = W[k * 128 + lane];
    w1[k] = W[k * 128 + 64 + lane];
  }
  float b0 = b[lane], b1 = b[lane + 64];
  float g0 = g[lane], g1 = g[lane + 64];
  float e0 = lb[lane], e1 = lb[lane + 64];
  for (int n = blockIdx.x * 4 + wid; n < M; n += gridDim.x * 4){
    const float4* xr = (const float4*)(x + (size_t)n * 32);
    float xs[32];
    #pragma unroll
    for (int q = 0; q < 8; q++){
      float4 t = xr[q];
      xs[4*q] = t.x; xs[4*q+1] = t.y; xs[4*q+2] = t.z; xs[4*q+3] = t.w;
    }
    float a0 = b0, a1 = b1;
    #pragma unroll
    for (int k = 0; k < 32; k++){ a0 += xs[k] * w0[k]; a1 += xs[k] * w1[k]; }
    h[(size_t)n * H + lane]      = a0;
    h[(size_t)n * H + lane + 64] = a1;
    float mu = wsum(a0 + a1) * (1.f / 128.f);
    float d0 = a0 - mu, d1 = a1 - mu;
    float var = wsum(d0 * d0 + d1 * d1) * (1.f / 128.f);
    float rs = rsqrtf(var + 1e-5f);
    xn[(size_t)n * H + lane]      = __float2bfloat16(d0 * rs * g0 + e0);
    xn[(size_t)n * H + lane + 64] = __float2bfloat16(d1 * rs * g1 + e1);
  }
}

// ---------- per-layer edge coefficients + well-path precompute (4 blocks) ----------
__global__ void coeff_k(const float* __restrict__ gWe, const float* __restrict__ gae,
    const float* __restrict__ Wee, const float* __restrict__ bee,
    float* __restrict__ coeff,
    const float* __restrict__ wW, const float* __restrict__ wad,
    const float* __restrict__ Wwell, const float* __restrict__ bwell,
    float* __restrict__ wvec)
{
  __shared__ float red[4];
  __shared__ float su[128];
  int t = threadIdx.x;   // 0..127
  int i = blockIdx.x;
  if (i < NL){
    const float* Wr = gWe + ((size_t)i * H + t) * H;
    const float* ga = gae + (size_t)i * H;
    float w = 0.f;
    for (int k = 0; k < H; k++) w += Wr[k] * ga[k];
    float pc = Wee[t] * w, pd = bee[t] * w;
    pc = wsum(pc); pd = wsum(pd);
    if ((t & 63) == 0){ red[(t >> 6) * 2 + 0] = pc; red[(t >> 6) * 2 + 1] = pd; }
    __syncthreads();
    if (t == 0){ coeff[i] = red[0] + red[2]; coeff[NL + i] = red[1] + red[3]; }
  } else {
    // u = wW @ wad ; v16 = W_well @ u ; c = b_well . u
    float u = 0.f;
    const float* wWr = wW + (size_t)t * H;
    for (int j = 0; j < H; j++) u += wWr[j] * wad[j];
    su[t] = u;
    __syncthreads();
    if (t < 16){
      float v = 0.f;
      for (int k = 0; k < H; k++) v += Wwell[t * H + k] * su[k];
      wvec[t] = v;
    }
    float pc = bwell[t] * su[t];
    pc = wsum(pc);
    if ((t & 63) == 0) red[t >> 6] = pc;
    __syncthreads();
    if (t == 0) wvec[16] = red[0] + red[1];
  }
}

// ---------- MFMA GEMM (layer 0): A in regs, frag-major W image -> LDS ----------
__global__ __launch_bounds__(512, 4) void gemm_mfma_k(
    const __hip_bfloat16* __restrict__ A, const char* __restrict__ Wimg,
    __hip_bfloat16* __restrict__ Cbf,
    const float* __restrict__ va, const float* __restrict__ vb,
    float* __restrict__ oa, float* __restrict__ ob, int M)
{
  __shared__ uint4 sW4[2048];
  char* sW = (char*)sW4;
  const int tid = threadIdx.x;
  const int lane = tid & 63, w = tid >> 6;
  const int n0 = blockIdx.x * 128;
  const int rw = w * 16;
  const int lr = lane & 15, lk = lane >> 4;

  {
    int go = w * 1024 + lane * 16;
    #pragma unroll
    for (int q = 0; q < 4; q++)
      gload16(Wimg + q * 8192 + go, sW + q * 8192 + w * 1024);
  }

  const int arow = n0 + rw + lr;
  bf16x8 aX[4];
  if (arow < M){
    #pragma unroll
    for (int ks = 0; ks < 4; ks++)
      aX[ks] = *(const bf16x8*)(A + (size_t)arow * 128 + ks * 32 + lk * 8);
  } else {
    #pragma unroll
    for (int ks = 0; ks < 4; ks++) aX[ks] = (bf16x8){0,0,0,0,0,0,0,0};
  }
  __syncthreads();

  f32x4 acc[8];
  #pragma unroll
  for (int i = 0; i < 8; i++) acc[i] = (f32x4){0.f, 0.f, 0.f, 0.f};
  #pragma unroll
  for (int ks = 0; ks < 4; ks++){
    #pragma unroll
    for (int nt = 0; nt < 8; nt++){
      bf16x8 b = *(const bf16x8*)(sW + ((ks << 3) + nt) * 1024 + (lane << 4));
      acc[nt] = MFMA16(aX[ks], b, acc[nt]);
    }
  }
  #pragma unroll
  for (int nt = 0; nt < 8; nt++){
    int col = nt * 16 + lr;
    #pragma unroll
    for (int r = 0; r < 4; r++){
      int row = n0 + rw + lk * 4 + r;
      if (row < M) Cbf[(size_t)row * 128 + col] = __float2bfloat16(acc[nt][r]);
    }
  }
  {
    float vac[8], vbc[8];
    #pragma unroll
    for (int nt = 0; nt < 8; nt++){
      vac[nt] = va[nt * 16 + lr];
      vbc[nt] = vb ? vb[nt * 16 + lr] : 0.f;
    }
    #pragma unroll
    for (int r = 0; r < 4; r++){
      float da = 0.f, db = 0.f;
      #pragma unroll
      for (int nt = 0; nt < 8; nt++){
        da += acc[nt][r] * vac[nt];
        db += acc[nt][r] * vbc[nt];
      }
      #pragma unroll
      for (int o = 1; o < 16; o <<= 1){
        da += __shfl_xor(da, o, 64);
        db += __shfl_xor(db, o, 64);
      }
      int row = n0 + rw + lk * 4 + r;
      if (lr == 0 && row < M){
        oa[row] = da;
        if (ob) ob[row] = db;
      }
    }
  }
}

// ---------- MEGA: GAT(i) + FFN(i) + GEMM(i+1), pipelined phase A ----------
__global__ __launch_bounds__(512, 4) void mega_k(
    const int* __restrict__ incl, const int* __restrict__ csr,
    const int* __restrict__ src, const float* __restrict__ attr,
    const float* __restrict__ coeff, int ci,
    const float* __restrict__ as_in, const float* __restrict__ ad_in,
    const __hip_bfloat16* __restrict__ X,
    const float* __restrict__ gbv,
    const float* __restrict__ n2gv, const float* __restrict__ n2bv,
    float* __restrict__ h,
    const char* __restrict__ W1img, const float* __restrict__ b1,
    const char* __restrict__ W2img, const float* __restrict__ b2,
    const float* __restrict__ lng, const float* __restrict__ lnb,
    const char* __restrict__ Wg,
    const float* __restrict__ va, const float* __restrict__ vb,
    float* __restrict__ oa, float* __restrict__ ob,
    __hip_bfloat16* __restrict__ Cbf, int mode, int M)
{
  __shared__ uint4 sW1_4[2][1024];
  __shared__ uint4 sW2_4[2][1024];
  __shared__ uint4 sT4[1024];
  char* sT = (char*)sT4;
  const int tid = threadIdx.x;
  const int lane = tid & 63, w = tid >> 6;
  const int n0 = blockIdx.x * 128;
  const int rw = w * 16;
  const int lr = lane & 15, lk = lane >> 4;
  const int gl = lane & 15, grp = lane >> 4;
  const int go = w * 1024 + lane * 16;
  const int lo = w * 1024;
  char* sTw = sT + w * 2048;
  char* aimgW = (w < 4) ? ((char*)sW1_4[1] + w * 4096)
                        : ((char*)sW2_4[1] + (w - 4) * 4096);

  gload16(W1img + go,        (char*)sW1_4[0] + lo);
  gload16(W1img + 8192 + go, (char*)sW1_4[0] + 8192 + lo);
  gload16(W2img + go,        (char*)sW2_4[0] + lo);
  gload16(W2img + 8192 + go, (char*)sW2_4[0] + 8192 + lo);

  const float c0 = coeff[ci], c1 = coeff[NL + ci];
  const int gbase = grp << 4;
  const int nb = n0 + w * 16 + grp * 4;

#define GACC2(A, U, P) \
    A[0] += (P) * __uint_as_float((U).x << 16); \
    A[1] += (P) * __uint_as_float((U).x & 0xffff0000u); \
    A[2] += (P) * __uint_as_float((U).y << 16); \
    A[3] += (P) * __uint_as_float((U).y & 0xffff0000u); \
    A[4] += (P) * __uint_as_float((U).z << 16); \
    A[5] += (P) * __uint_as_float((U).z & 0xffff0000u); \
    A[6] += (P) * __uint_as_float((U).w << 16); \
    A[7] += (P) * __uint_as_float((U).w & 0xffff0000u);

#define NODE_EPI(Q, ACC) { \
    int n = nb + (Q); \
    char* adst = aimgW + ((gl >> 2) << 10) + ((((gl & 3) << 4) + grp * 4 + (Q)) << 4); \
    if (n >= M){ *(uint4*)adst = make_uint4(0u,0u,0u,0u); } else { \
      float inv = (s4[Q] == 0.f) ? 0.f : 1.f / s4[Q]; \
      int j0 = gl * 8; \
      float4 h0 = *(float4*)&h[(size_t)n * H + j0]; \
      float4 h1 = *(float4*)&h[(size_t)n * H + j0 + 4]; \
      float4 g0 = *(const float4*)&gbv[j0]; \
      float4 g1 = *(const float4*)&gbv[j0 + 4]; \
      float hv[8]; \
      hv[0] = h0.x + ACC[0]*inv + g0.x; hv[1] = h0.y + ACC[1]*inv + g0.y; \
      hv[2] = h0.z + ACC[2]*inv + g0.z; hv[3] = h0.w + ACC[3]*inv + g0.w; \
      hv[4] = h1.x + ACC[4]*inv + g1.x; hv[5] = h1.y + ACC[5]*inv + g1.y; \
      hv[6] = h1.z + ACC[6]*inv + g1.z; hv[7] = h1.w + ACC[7]*inv + g1.w; \
      float ls = 0.f; \
      _Pragma("unroll") for (int i = 0; i < 8; i++) ls += hv[i]; \
      float mu = gsum16(ls) * (1.f / H); \
      float vs = 0.f; \
      _Pragma("unroll") for (int i = 0; i < 8; i++){ float d = hv[i]-mu; vs += d*d; } \
      float var = gsum16(vs) * (1.f / H); \
      float rsq = rsqrtf(var + 1e-5f); \
      float4 o0, o1; \
      o0.x=hv[0]; o0.y=hv[1]; o0.z=hv[2]; o0.w=hv[3]; \
      o1.x=hv[4]; o1.y=hv[5]; o1.z=hv[6]; o1.w=hv[7]; \
      *(float4*)&h[(size_t)n * H + j0] = o0; \
      *(float4*)&h[(size_t)n * H + j0 + 4] = o1; \
      float4 gg0 = *(const float4*)&n2gv[j0]; \
      float4 gg1 = *(const float4*)&n2gv[j0 + 4]; \
      float4 bb0 = *(const float4*)&n2bv[j0]; \
      float4 bb1 = *(const float4*)&n2bv[j0 + 4]; \
      float xo[8]; \
      xo[0]=(hv[0]-mu)*rsq*gg0.x+bb0.x; xo[1]=(hv[1]-mu)*rsq*gg0.y+bb0.y; \
      xo[2]=(hv[2]-mu)*rsq*gg0.z+bb0.z; xo[3]=(hv[3]-mu)*rsq*gg0.w+bb0.w; \
      xo[4]=(hv[4]-mu)*rsq*gg1.x+bb1.x; xo[5]=(hv[5]-mu)*rsq*gg1.y+bb1.y; \
      xo[6]=(hv[6]-mu)*rsq*gg1.z+bb1.z; xo[7]=(hv[7]-mu)*rsq*gg1.w+bb1.w; \
      uint4 ow; unsigned* owp = (unsigned*)&ow; \
      _Pragma("unroll") for (int i = 0; i < 4; i++){ \
        __hip_bfloat16 lo2 = __float2bfloat16(xo[2*i]); \
        __hip_bfloat16 hi2 = __float2bfloat16(xo[2*i+1]); \
        owp[i] = ((unsigned)(*(unsigned short*)&hi2) << 16) | (*(unsigned short*)&lo2); \
      } \
      *(uint4*)adst = ow; \
    } }

  // ---- phase A ----
  int beg4[4], cnt4[4];
  #pragma unroll
  for (int q = 0; q < 4; q++){
    int n = nb + q;
    if (n < M){
      int b0 = (n == 0) ? 0 : incl[n - 1];
      beg4[q] = b0;
      cnt4[q] = incl[n] - b0;
    } else { beg4[q] = 0; cnt4[q] = 0; }
  }
  bool big = (cnt4[0] > 16) || (cnt4[1] > 16) || (cnt4[2] > 16) || (cnt4[3] > 16);

  if (!__any(big)){
    float adn4[4];
    #pragma unroll
    for (int q = 0; q < 4; q++) adn4[q] = (nb + q < M) ? ad_in[nb + q] : 0.f;
    int e4[4];
    #pragma unroll
    for (int q = 0; q < 4; q++) e4[q] = (gl < cnt4[q]) ? csr[beg4[q] + gl] : 0;
    int sv4[4];
    #pragma unroll
    for (int q = 0; q < 4; q++) sv4[q] = (gl < cnt4[q]) ? src[e4[q]] : 0;
    float at4[4];
    #pragma unroll
    for (int q = 0; q < 4; q++) at4[q] = (gl < cnt4[q]) ? attr[e4[q]] : 0.f;
    float as4[4];
    #pragma unroll
    for (int q = 0; q < 4; q++) as4[q] = (gl < cnt4[q]) ? as_in[sv4[q]] : 0.f;
    float p4[4], s4[4];
    #pragma unroll
    for (int q = 0; q < 4; q++){
      bool v = gl < cnt4[q];
      float a = v ? (as4[q] + adn4[q] + at4[q] * c0 + c1) : -1e30f;
      a = (a > 0.f) ? a : 0.2f * a;
      float mq = gmax16(a);
      float p = v ? expf(a - mq) : 0.f;
      s4[q] = gsum16(p);
      p4[q] = p;
    }
    #pragma unroll
    for (int qp = 0; qp < 2; qp++){
      const int q0 = qp * 2, q1 = qp * 2 + 1;
      float accA[8], accB[8];
      #pragma unroll
      for (int i = 0; i < 8; i++){ accA[i] = 0.f; accB[i] = 0.f; }
      int cm = max(cnt4[q0], cnt4[q1]);
      for (int t = 0; t < cm; t += 2){
        float pa0 = __shfl(p4[q0], gbase + t, 64);
        float pb0 = __shfl(p4[q1], gbase + t, 64);
        float pa1 = __shfl(p4[q0], gbase + t + 1, 64);
        float pb1 = __shfl(p4[q1], gbase + t + 1, 64);
        int sa0 = __shfl(sv4[q0], gbase + t, 64);
        int sb0 = __shfl(sv4[q1], gbase + t, 64);
        int sa1 = __shfl(sv4[q0], gbase + t + 1, 64);
        int sb1 = __shfl(sv4[q1], gbase + t + 1, 64);
        uint4 ua0 = *(const uint4*)(X + (size_t)sa0 * H + gl * 8);
        uint4 ub0 = *(const uint4*)(X + (size_t)sb0 * H + gl * 8);
        uint4 ua1 = *(const uint4*)(X + (size_t)sa1 * H + gl * 8);
        uint4 ub1 = *(const uint4*)(X + (size_t)sb1 * H + gl * 8);
        GACC2(accA, ua0, pa0) GACC2(accB, ub0, pb0)
        GACC2(accA, ua1, pa1) GACC2(accB, ub1, pb1)
      }
      NODE_EPI(q0, accA)
      NODE_EPI(q1, accB)
    }
  } else {
    for (int q = 0; q < 4; q++){
      int n = nb + q;
      char* adst = aimgW + ((gl >> 2) << 10) + ((((gl & 3) << 4) + grp * 4 + q) << 4);
      if (n >= M){ *(uint4*)adst = make_uint4(0u,0u,0u,0u); continue; }
      int beg = beg4[q];
      int end = beg4[q] + cnt4[q];
      float adn = ad_in[n];
      float m = -1e30f, s = 0.f;
      float acc[8];
      #pragma unroll
      for (int i = 0; i < 8; i++) acc[i] = 0.f;
      for (int base = beg; base < end; base += 16){
        int idx = base + gl;
        bool valid = idx < end;
        int e = valid ? csr[idx] : 0;
        int sv = valid ? src[e] : 0;
        float a = -1e30f;
        if (valid){
          a = as_in[sv] + adn + attr[e] * c0 + c1;
          a = (a > 0.f) ? a : 0.2f * a;
        }
        float cmx = gmax16(a);
        float nm = fmaxf(m, cmx);
        float sc = expf(m - nm);
        #pragma unroll
        for (int i = 0; i < 8; i++) acc[i] *= sc;
        s *= sc;
        float p = valid ? expf(a - nm) : 0.f;
        s += gsum16(p);
        m = nm;
        int cnt = min(16, end - base);
        for (int t = 0; t < cnt; t++){
          float pt = __shfl(p, gbase + t, 64);
          int st = __shfl(sv, gbase + t, 64);
          uint4 u = *(const uint4*)(X + (size_t)st * H + gl * 8);
          GACC2(acc, u, pt)
        }
      }
      float s4q = s;
      float s4[4]; s4[q] = s4q;
      NODE_EPI(q, acc)
    }
  }
#undef GACC2

  asm volatile("s_waitcnt lgkmcnt(0)" ::: "memory");
  bf16x8 aX[4];
  #pragma unroll
  for (int ks = 0; ks < 4; ks++)
    aX[ks] = *(const bf16x8*)(aimgW + (ks << 10) + (lane << 4));
  asm volatile("s_waitcnt lgkmcnt(0) vmcnt(0)" ::: "memory");
  __builtin_amdgcn_s_barrier();

  f32x4 acc2[8];
  #pragma unroll
  for (int i = 0; i < 8; i++) acc2[i] = (f32x4){0.f, 0.f, 0.f, 0.f};

  const int rdA = ((lane ^ ((lane >> 3) & 7)) << 4);

  for (int ch = 0; ch < DFF / DC; ch++){
    const int cur = ch & 1;
    if (ch < DFF / DC - 1){
      const char* g1 = W1img + (size_t)(ch + 1) * 16384;
      const char* g2 = W2img + (size_t)(ch + 1) * 16384;
      char* d1 = (char*)sW1_4[cur ^ 1];
      char* d2 = (char*)sW2_4[cur ^ 1];
      gload16(g1 + go,        d1 + lo);
      gload16(g1 + 8192 + go, d1 + 8192 + lo);
      gload16(g2 + go,        d2 + lo);
      gload16(g2 + 8192 + go, d2 + 8192 + lo);
    } else {
      gload16(Wg + go,         (char*)sW1_4[0] + lo);
      gload16(Wg + 8192 + go,  (char*)sW1_4[0] + 8192 + lo);
      gload16(Wg + 16384 + go, (char*)sW2_4[0] + lo);
      gload16(Wg + 24576 + go, (char*)sW2_4[0] + 8192 + lo);
    }

    const char* W1c = (const char*)sW1_4[cur];
    const char* W2c = (const char*)sW2_4[cur];

    f32x4 acc1[4];
    #pragma unroll
    for (int i = 0; i < 4; i++) acc1[i] = (f32x4){0.f, 0.f, 0.f, 0.f};
    #pragma unroll
    for (int ks = 0; ks < 4; ks++){
      #pragma unroll
      for (int nt = 0; nt < 4; nt++){
        bf16x8 b = *(const bf16x8*)(W1c + ((ks << 2) + nt) * 1024 + (lane << 4));
        acc1[nt] = MFMA16(aX[ks], b, acc1[nt]);
      }
    }
    #pragma unroll
    for (int nt = 0; nt < 4; nt++){
      int col = nt * 16 + lr;
      float bb = b1[ch * DC + col];
      int ksp = col >> 5;
      int qhi = ((col >> 3) & 3) << 4;
      int jb  = (col & 7) << 1;
      #pragma unroll
      for (int r = 0; r < 4; r++){
        int slot = qhi + lk * 4 + r;
        int slotp = slot ^ ((slot >> 3) & 7);
        float v = fmaxf(acc1[nt][r] + bb, 0.f);
        *(__hip_bfloat16*)(sTw + (ksp << 10) + (slotp << 4) + jb) = __float2bfloat16(v);
      }
    }
    asm volatile("s_waitcnt lgkmcnt(0)" ::: "memory");

    #pragma unroll
    for (int ks = 0; ks < 2; ks++){
      bf16x8 a = *(const bf16x8*)(sTw + (ks << 10) + rdA);
      #pragma unroll
      for (int nt = 0; nt < 8; nt++){
        bf16x8 b = *(const bf16x8*)(W2c + ((ks << 3) + nt) * 1024 + (lane << 4));
        acc2[nt] = MFMA16(a, b, acc2[nt]);
      }
    }
    if (ch < DFF / DC - 1){
      asm volatile("s_waitcnt vmcnt(0)" ::: "memory");
      __builtin_amdgcn_s_barrier();
    }
  }

  asm volatile("s_waitcnt vmcnt(0)" ::: "memory");
  __builtin_amdgcn_s_barrier();

  float b2c[8];
  #pragma unroll
  for (int nt = 0; nt < 8; nt++) b2c[nt] = b2[nt * 16 + lr];
  float lngc[8], lnbc[8];
  if (mode == 0){
    #pragma unroll
    for (int nt = 0; nt < 8; nt++){
      lngc[nt] = lng[nt * 16 + lr];
      lnbc[nt] = lnb[nt * 16 + lr];
    }
  }

  #pragma unroll
  for (int r = 0; r < 4; r++){
    int row = n0 + rw + lk * 4 + r;
    bool ok = row < M;
    float val[8]; float sum = 0.f;
    #pragma unroll
    for (int nt = 0; nt < 8; nt++){
      int col = nt * 16 + lr;
      float hv = ok ? h[(size_t)row * 128 + col] : 0.f;
      val[nt] = hv + acc2[nt][r] + b2c[nt];
      sum += val[nt];
    }
    float mu = 0.f, rs = 1.f;
    if (mode == 0){
      #pragma unroll
      for (int o = 1; o < 16; o <<= 1) sum += __shfl_xor(sum, o, 64);
      mu = sum * (1.f / 128.f);
      float vs = 0.f;
      #pragma unroll
      for (int nt = 0; nt < 8; nt++){ float d = val[nt] - mu; vs += d * d; }
      #pragma unroll
      for (int o = 1; o < 16; o <<= 1) vs += __shfl_xor(vs, o, 64);
      rs = rsqrtf(vs * (1.f / 128.f) + 1e-5f);
    }
    #pragma unroll
    for (int nt = 0; nt < 8; nt++){
      int col = nt * 16 + lr;
      if (mode == 0 && ok) h[(size_t)row * 128 + col] = val[nt];
      float xo = (mode == 0) ? ((val[nt] - mu) * rs * lngc[nt] + lnbc[nt]) : val[nt];
      int lanep = ((((nt & 1) << 1) + (lr >> 3)) << 4) + (lk << 2) + r;
      *(__hip_bfloat16*)(aimgW + ((nt >> 1) << 10) + (lanep << 4) + ((lr & 7) << 1)) =
          __float2bfloat16(xo);
    }
  }
  asm volatile("s_waitcnt lgkmcnt(0)" ::: "memory");

  bf16x8 aG[4];
  #pragma unroll
  for (int ks = 0; ks < 4; ks++)
    aG[ks] = *(const bf16x8*)(aimgW + (ks << 10) + (lane << 4));
  f32x4 accG[8];
  #pragma unroll
  for (int i = 0; i < 8; i++) accG[i] = (f32x4){0.f, 0.f, 0.f, 0.f};
  #pragma unroll
  for (int ks = 0; ks < 4; ks++){
    #pragma unroll
    for (int nt = 0; nt < 8; nt++){
      const char* bptr = (ks < 2)
          ? ((const char*)sW1_4[0] + (((ks << 3) + nt) << 10) + (lane << 4))
          : ((const char*)sW2_4[0] + ((((ks - 2) << 3) + nt) << 10) + (lane << 4));
      accG[nt] = MFMA16(aG[ks], *(const bf16x8*)bptr, accG[nt]);
    }
  }
  #pragma unroll
  for (int nt = 0; nt < 8; nt++){
    int col = nt * 16 + lr;
    #pragma unroll
    for (int r = 0; r < 4; r++){
      int row = n0 + rw + lk * 4 + r;
      if (row < M) Cbf[(size_t)row * 128 + col] = __float2bfloat16(accG[nt][r]);
    }
  }
  {
    float vac[8], vbc[8];
    #pragma unroll
    for (int nt = 0; nt < 8; nt++){
      vac[nt] = va[nt * 16 + lr];
      vbc[nt] = vb ? vb[nt * 16 + lr] : 0.f;
    }
    #pragma unroll
    for (int r = 0; r < 4; r++){
      float da = 0.f, db = 0.f;
      #pragma unroll
      for (int nt = 0; nt < 8; nt++){
        da += accG[nt][r] * vac[nt];
        db += accG[nt][r] * vbc[nt];
      }
      #pragma unroll
      for (int o = 1; o < 16; o <<= 1){
        da += __shfl_xor(da, o, 64);
        db += __shfl_xor(db, o, 64);
      }
      int row = n0 + rw + lk * 4 + r;
      if (lr == 0 && row < M){
        oa[row] = da;
        if (ob) ob[row] = db;
      }
    }
  }
#undef NODE_EPI
}

// ---------- CSR build (c2c, multi-kernel) ----------
__global__ void count_k(const int* __restrict__ dst, int* __restrict__ cnt, int NE){
  int e = blockIdx.x * 256 + threadIdx.x;
  if (e < NE) atomicAdd(&cnt[dst[e]], 1);
}
__global__ void scan1_k(const int* __restrict__ in, int* __restrict__ out,
                        int* __restrict__ bsum, int N){
  __shared__ int sd[256];
  int tid = threadIdx.x;
  int base = blockIdx.x * 1024 + tid * 4;
  int v0 = (base + 0 < N) ? in[base + 0] : 0;
  int v1 = (base + 1 < N) ? in[base + 1] : 0;
  int v2 = (base + 2 < N) ? in[base + 2] : 0;
  int v3 = (base + 3 < N) ? in[base + 3] : 0;
  sd[tid] = v0 + v1 + v2 + v3;
  __syncthreads();
  for (int off = 1; off < 256; off <<= 1){
    int t = (tid >= off) ? sd[tid - off] : 0;
    __syncthreads();
    sd[tid] += t;
    __syncthreads();
  }
  int run = (tid > 0) ? sd[tid - 1] : 0;
  run += v0; if (base + 0 < N) out[base + 0] = run;
  run += v1; if (base + 1 < N) out[base + 1] = run;
  run += v2; if (base + 2 < N) out[base + 2] = run;
  run += v3; if (base + 3 < N) out[base + 3] = run;
  if (tid == 255) bsum[blockIdx.x] = sd[255];
}
__global__ void scan2_k(int* __restrict__ bs, int NB){
  __shared__ int sd[256];
  int tid = threadIdx.x;
  int base = tid * 4;
  int v0 = (base + 0 < NB) ? bs[base + 0] : 0;
  int v1 = (base + 1 < NB) ? bs[base + 1] : 0;
  int v2 = (base + 2 < NB) ? bs[base + 2] : 0;
  int v3 = (base + 3 < NB) ? bs[base + 3] : 0;
  sd[tid] = v0 + v1 + v2 + v3;
  __syncthreads();
  for (int off = 1; off < 256; off <<= 1){
    int t = (tid >= off) ? sd[tid - off] : 0;
    __syncthreads();
    sd[tid] += t;
    __syncthreads();
  }
  int run = (tid > 0) ? sd[tid - 1] : 0;
  run += v0; if (base + 0 < NB) bs[base + 0] = run;
  run += v1; if (base + 1 < NB) bs[base + 1] = run;
  run += v2; if (base + 2 < NB) bs[base + 2] = run;
  run += v3; if (base + 3 < NB) bs[base + 3] = run;
}
// scan3 + initfill fused: finalize incl and emit fill[i+1] = incl_final[i]
__global__ void scan3f_k(int* __restrict__ out, const int* __restrict__ bsum,
                         int* __restrict__ fill, int N){
  int b = blockIdx.x;
  int add = (b == 0) ? 0 : bsum[b - 1];
  int i = b * 1024 + threadIdx.x * 4;
  #pragma unroll
  for (int j = 0; j < 4; j++){
    if (i + j < N){
      int v = out[i + j] + add;
      if (b > 0) out[i + j] = v;
      if (i + j + 1 < N) fill[i + j + 1] = v;
    }
  }
  if (b == 0 && threadIdx.x == 0) fill[0] = 0;
}
__global__ void fill_k(const int* __restrict__ dst, int* __restrict__ fill,
                       int* __restrict__ csr, int NE){
  int e = blockIdx.x * 256 + threadIdx.x;
  if (e < NE){
    int p = atomicAdd(&fill[dst[e]], 1);
    csr[p] = e;
  }
}

// ---------- CSR build (c2w) fused in ONE single-block kernel ----------
__global__ __launch_bounds__(1024) void csrw_k(const int* __restrict__ wdst,
    int* __restrict__ inclW, int* __restrict__ csrW)
{
  __shared__ int cnt[512];
  __shared__ int sc[512];
  int t = threadIdx.x;  // 0..1023
  if (t < 512) cnt[t] = 0;
  __syncthreads();
  for (int e = t; e < NE_CW; e += 1024) atomicAdd(&cnt[wdst[e]], 1);
  __syncthreads();
  if (t < 512) sc[t] = cnt[t];
  __syncthreads();
  for (int off = 1; off < 512; off <<= 1){
    int v = 0;
    if (t < 512 && t >= off) v = sc[t - off];
    __syncthreads();
    if (t < 512) sc[t] += v;
    __syncthreads();
  }
  if (t < NW) inclW[t] = sc[t];
  if (t < 512) cnt[t] = (t == 0) ? 0 : sc[t - 1];   // exclusive offsets
  __syncthreads();
  for (int e = t; e < NE_CW; e += 1024){
    int p = atomicAdd(&cnt[wdst[e]], 1);
    csrW[p] = e;
  }
}

// ---------- standalone GAT gather (wells; adn computed inline from well_x) ----------
__global__ __launch_bounds__(256) void gat_k(
    const int* __restrict__ incl, const int* __restrict__ csr,
    const int* __restrict__ src,
    const float* __restrict__ as_,
    const float* __restrict__ wellx, const float* __restrict__ wv,
    const __hip_bfloat16* __restrict__ X, float* __restrict__ hout, int M)
{
  int lane = threadIdx.x & 63, wid = threadIdx.x >> 6;
  int grp = lane >> 4, gl = lane & 15;
  int n = blockIdx.x * 16 + wid * 4 + grp;
  if (n >= M) return;
  int beg = (n == 0) ? 0 : incl[n - 1];
  int end = incl[n];
  // adn = well_x[n] . v16 + c   (algebraic collapse of hw@wW@wad)
  float adn = gsum16(wellx[(size_t)n * 16 + gl] * wv[gl]) + wv[16];
  const int gbase = grp << 4;
  float m = -1e30f, s = 0.f;
  float acc[8];
  #pragma unroll
  for (int i = 0; i < 8; i++) acc[i] = 0.f;
#define GACC(U, P) \
    acc[0] += (P) * __uint_as_float((U).x << 16); \
    acc[1] += (P) * __uint_as_float((U).x & 0xffff0000u); \
    acc[2] += (P) * __uint_as_float((U).y << 16); \
    acc[3] += (P) * __uint_as_float((U).y & 0xffff0000u); \
    acc[4] += (P) * __uint_as_float((U).z << 16); \
    acc[5] += (P) * __uint_as_float((U).z & 0xffff0000u); \
    acc[6] += (P) * __uint_as_float((U).w << 16); \
    acc[7] += (P) * __uint_as_float((U).w & 0xffff0000u);
  for (int base = beg; base < end; base += 16){
    int idx = base + gl;
    bool valid = idx < end;
    int e = valid ? csr[idx] : 0;
    int sv = valid ? src[e] : 0;
    float a = -1e30f;
    if (valid){
      a = as_[sv] + adn;
      a = (a > 0.f) ? a : 0.2f * a;
    }
    float cm = gmax16(a);
    float nm = fmaxf(m, cm);
    float sc = expf(m - nm);
    #pragma unroll
    for (int i = 0; i < 8; i++) acc[i] *= sc;
    s *= sc;
    float p = valid ? expf(a - nm) : 0.f;
    s += gsum16(p);
    m = nm;
    int cnt = min(16, end - base);
    for (int t = 0; t < cnt; t++){
      float pt = __shfl(p, gbase + t, 64);
      int st = __shfl(sv, gbase + t, 64);
      uint4 u = *(const uint4*)(X + (size_t)st * H + gl * 8);
      GACC(u, pt)
    }
  }
#undef GACC
  float inv = (s == 0.f) ? 0.f : 1.f / s;
  int j0 = gl * 8;
  float4 o0, o1;
  o0.x = acc[0]*inv; o0.y = acc[1]*inv; o0.z = acc[2]*inv; o0.w = acc[3]*inv;
  o1.x = acc[4]*inv; o1.y = acc[5]*inv; o1.z = acc[6]*inv; o1.w = acc[7]*inv;
  *(float4*)&hout[(size_t)n * H + j0] = o0;
  *(float4*)&hout[(size_t)n * H + j0 + 4] = o1;
}

// ---------- final well MLP ----------
__global__ __launch_bounds__(128) void mlp_k(const float* __restrict__ hwell,
    const float* __restrict__ wb, const float* __restrict__ mW1,
    const float* __restrict__ mb1, const float* __restrict__ mW2,
    const float* __restrict__ mb2, float* __restrict__ out)
{
  __shared__ float sH[128], sT[128];
  int n = blockIdx.x, j = threadIdx.x;
  sH[j] = hwell[(size_t)n * H + j] + wb[j];
  __syncthreads();
  float a = mb1[j];
  for (int k = 0; k < 128; k++) a += sH[k] * mW1[k * 128 + j];
  sT[j] = fmaxf(a, 0.f);
  __syncthreads();
  if (j < 75){
    float o = mb2[j];
    for (int k = 0; k < 128; k++) o += sT[k] * mW2[k * 75 + j];
    out[(size_t)n * 75 + j] = o;
  }
}

extern "C" void kernel_launch(void* const* d_in, const int* in_sizes, int n_in,
                              void* d_out, int out_size, void* d_ws, size_t ws_size,
                              hipStream_t stream)
{
  (void)in_sizes; (void)n_in; (void)out_size; (void)ws_size;
  const float* cell_x = (const float*)d_in[0];
  const float* well_x = (const float*)d_in[1];
  const int*   eidx   = (const int*)d_in[2];
  const float* eattr  = (const float*)d_in[3];
  const int*   wsrc   = (const int*)d_in[4];
  const int*   wdst   = (const int*)d_in[5];
  const float* W_cell = (const float*)d_in[6];
  const float* b_cell = (const float*)d_in[7];
  const float* W_well = (const float*)d_in[8];
  const float* b_well = (const float*)d_in[9];
  const float* W_ee   = (const float*)d_in[10];
  const float* b_ee   = (const float*)d_in[11];
  const float* gW     = (const float*)d_in[12];
  const float* gas    = (const float*)d_in[13];
  const float* gad    = (const float*)d_in[14];
  const float* gae    = (const float*)d_in[15];
  const float* gWe    = (const float*)d_in[16];
  const float* gb     = (const float*)d_in[17];
  const float* n1g    = (const float*)d_in[18];
  const float* n1b    = (const float*)d_in[19];
  const float* fW1    = (const float*)d_in[20];
  const float* fb1    = (const float*)d_in[21];
  const float* fW2    = (const float*)d_in[22];
  const float* fb2    = (const float*)d_in[23];
  const float* n2g    = (const float*)d_in[24];
  const float* n2b    = (const float*)d_in[25];
  const float* wW     = (const float*)d_in[26];
  const float* was    = (const float*)d_in[27];
  const float* wad    = (const float*)d_in[28];
  const float* wb     = (const float*)d_in[29];
  const float* mW1    = (const float*)d_in[30];
  const float* mb1    = (const float*)d_in[31];
  const float* mW2    = (const float*)d_in[32];
  const float* mb2    = (const float*)d_in[33];

  const int* src = eidx;
  const int* dst = eidx + NE_CC;

  char* wsb = (char*)d_ws;
  size_t off = 0;
  auto alloc = [&](size_t bytes) -> void* {
    void* p = wsb + off; off += (bytes + 255) & ~(size_t)255; return p;
  };
  float* h      = (float*)alloc((size_t)NC * H * 4);
  __hip_bfloat16* xnbf  = (__hip_bfloat16*)alloc((size_t)NC * H * 2);
  __hip_bfloat16* hsbf0 = (__hip_bfloat16*)alloc((size_t)NC * H * 2);
  __hip_bfloat16* hsbf1 = (__hip_bfloat16*)alloc((size_t)NC * H * 2);
  float* as0    = (float*)alloc((size_t)NC * 4);
  float* ad0    = (float*)alloc((size_t)NC * 4);
  float* as1    = (float*)alloc((size_t)NC * 4);
  float* ad1    = (float*)alloc((size_t)NC * 4);
  float* hwell  = (float*)alloc((size_t)NW * H * 4);
  float* coeff  = (float*)alloc(64);
  float* wvec   = (float*)alloc(128);
  char* gWimg = (char*)alloc((size_t)NL * 32768);
  char* wWimg = (char*)alloc(32768);
  char* W1img = (char*)alloc((size_t)NL * 131072);
  char* W2img = (char*)alloc((size_t)NL * 131072);
  int* cntC  = (int*)alloc((size_t)NC * 4);
  int* inclC = (int*)alloc((size_t)NC * 4);
  int* fillC = (int*)alloc((size_t)NC * 4);
  int* csrC  = (int*)alloc((size_t)NE_CC * 4);
  int* inclW = (int*)alloc((size_t)NW * 4);
  int* csrW  = (int*)alloc((size_t)NE_CW * 4);
  int* bsum  = (int*)alloc(1024 * 4);

  const int eBlocks = (NE_CC + 255) / 256;
  const int NBC = (NC + 1023) / 1024;

  // ---- CSR build (c2c) ----
  hipMemsetAsync(cntC, 0, (size_t)NC * 4, stream);
  count_k<<<eBlocks, 256, 0, stream>>>(dst, cntC, NE_CC);
  scan1_k<<<NBC, 256, 0, stream>>>(cntC, inclC, bsum, NC);
  scan2_k<<<1, 256, 0, stream>>>(bsum, NBC);
  scan3f_k<<<NBC, 256, 0, stream>>>(inclC, bsum, fillC, NC);
  fill_k<<<eBlocks, 256, 0, stream>>>(dst, fillC, csrC, NE_CC);
  // ---- CSR build (c2w): one kernel ----
  csrw_k<<<1, 1024, 0, stream>>>(wdst, inclW, csrW);

  // ---- weight image prep ----
  prep_imgGW_k<<<96, 256, 0, stream>>>(gW, gWimg, NL);
  prep_imgGW_k<<<32, 256, 0, stream>>>(wW, wWimg, 1);
  prep_imgW1_k<<<768, 256, 0, stream>>>(fW1, W1img);
  prep_imgW2_k<<<768, 256, 0, stream>>>(fW2, W2img);

  embed_ln_k<<<1024, 256, 0, stream>>>(cell_x, W_cell, b_cell, n1g, n1b, h, xnbf, NC);
  coeff_k<<<4, 128, 0, stream>>>(gWe, gae, W_ee, b_ee, coeff,
                                 wW, wad, W_well, b_well, wvec);

  const int mfmaBlocks = (NC + 127) / 128;

  gemm_mfma_k<<<mfmaBlocks, 512, 0, stream>>>(xnbf, gWimg,
      hsbf0, gas, gad, as0, ad0, NC);

  for (int i = 0; i < NL; i++){
    const __hip_bfloat16* Xin = (i & 1) ? hsbf1 : hsbf0;
    __hip_bfloat16* Xout      = (i & 1) ? hsbf0 : hsbf1;
    const float* asi = (i & 1) ? as1 : as0;
    const float* adi = (i & 1) ? ad1 : ad0;
    float* aso = (i & 1) ? as0 : as1;
    float* ado = (i & 1) ? ad0 : ad1;
    if (i < NL - 1){
      mega_k<<<mfmaBlocks, 512, 0, stream>>>(inclC, csrC, src, eattr, coeff, i,
          asi, adi, Xin, gb + i * H, n2g + i * H, n2b + i * H, h,
          W1img + (size_t)i * 131072, fb1 + (size_t)i * DFF,
          W2img + (size_t)i * 131072, fb2 + (size_t)i * H,
          n1g + (i + 1) * H, n1b + (i + 1) * H,
          gWimg + (size_t)(i + 1) * 32768,
          gas + (i + 1) * H, gad + (i + 1) * H, aso, ado, Xout, 0, NC);
    } else {
      mega_k<<<mfmaBlocks, 512, 0, stream>>>(inclC, csrC, src, eattr, coeff, i,
          asi, adi, Xin, gb + i * H, n2g + i * H, n2b + i * H, h,
          W1img + (size_t)i * 131072, fb1 + (size_t)i * DFF,
          W2img + (size_t)i * 131072, fb2 + (size_t)i * H,
          n1g, n1b,
          wWimg, was, nullptr, aso, nullptr, Xout, 1, NC);
    }
  }
  // after i=2: Xout = hsbf1 (hc bf16), aso = as1

  // cell -> well bipartite GAT (adn computed inline from well_x via wvec)
  gat_k<<<(NW + 15) / 16, 256, 0, stream>>>(inclW, csrW, wsrc,
      as1, well_x, wvec, hsbf1, hwell, NW);
  mlp_k<<<NW, 128, 0, stream>>>(hwell, wb, mW1, mb1, mW2, mb2, (float*)d_out);
}